// Round 20
// 837.678 us; speedup vs baseline: 2.6289x; 1.0245x over previous
//
#include <hip/hip_runtime.h>
#include <hip/hip_bf16.h>
#include <math.h>

// FNO2d: B=8, S=192, pad->201x201, C=64, modes 12x12, 4 layers.
// Pixel-major activations [b][p][c]; MFMA conv GEMMs; MFMA forward-W (dftw),
// MFMA H-DFT (dfthM), MFMA inverse-W (ispec); chunked Parseval Gram;
// MFMA bypass Gram v2; fast sigmoid-gelu with folded GN coefficients.

#define NN 201
#define SS 192
#define NPIX 40401
#define QPIX 36864
#define BB 8
#define GNB 80           // gram slabs per b, 512 px each (one slab per wave)
#define XWPL 1234944     // 1608*12*64 (per-plane element stride; now bf16)
#define PI_F 3.14159265358979323846f

typedef __hip_bfloat16 bf16;
typedef __attribute__((ext_vector_type(8))) short s8v;
typedef __attribute__((ext_vector_type(4))) float f32x4;

// tanh-form gelu via sigmoid: x*sigma(1.5957691x + 0.0713548x^3); |err| <= ~1e-3
__device__ __forceinline__ float gelu_f(float x){
  float x2 = x*x;
  float t  = fmaf(x2, 0.0713548162f, 1.5957691216f);
  float e  = __expf(-x*t);
  return x*__builtin_amdgcn_rcpf(1.0f+e);
}
__device__ __forceinline__ float b2f(bf16 v){ return __bfloat162float(v); }
__device__ __forceinline__ bf16  f2b(float v){ return __float2bfloat16(v); }
__device__ __forceinline__ unsigned short f2bu(float x){
  bf16 h = __float2bfloat16(x);
  unsigned short u; __builtin_memcpy(&u,&h,2); return u;
}
__device__ __forceinline__ float bu2f(unsigned short u){
  unsigned int x = ((unsigned int)u)<<16; float f; __builtin_memcpy(&f,&x,4); return f;
}

// tab[k][n]: cos/sin(2*pi*k*n/201), k=0..12, exact mod-201 reduction
__global__ void k_tab(float* __restrict__ tab){
  int t = blockIdx.x*blockDim.x+threadIdx.x;
  if(t>=13*NN) return;
  int k=t/NN, n=t-k*NN;
  int m=(k*n)%NN;
  float ang = (2.0f*PI_F/201.0f)*(float)m;
  tab[2*t]   = cosf(ang);
  tab[2*t+1] = sinf(ang);
}

// Pack inverse-W twiddles into MFMA A-fragment order (bf16).
__global__ void k_tpack(const float* __restrict__ tab, unsigned short* __restrict__ TPK){
  int e = blockIdx.x*256 + threadIdx.x;
  if(e>=6656) return;
  int wt=e>>9, lane=(e>>3)&63, j=e&7;
  int m_=lane&15, g=lane>>4;
  int w = wt*16+m_;
  int k24 = g*8+j;
  float v=0.f;
  if(k24<24 && w<201){
    float2 cs = ((const float2*)tab)[(k24>>1)*NN + w];
    v = (k24&1)? cs.y : cs.x;
  }
  TPK[e]=f2bu(v);
}

// Pack forward-W twiddles into MFMA A-fragment order (bf16), sign folded.
__global__ void k_tpack2(const float* __restrict__ tab, unsigned short* __restrict__ T2PK){
  int e = blockIdx.x*256 + threadIdx.x;
  if(e>=7168) return;
  int idx = e>>9;
  int mt = idx/7, chunk = idx - mt*7;
  int lane=(e>>3)&63, j=e&7;
  int m_=lane&15, g=lane>>4;
  int kx24 = mt*16 + m_;
  int w = chunk*32 + g*8 + j;
  float v=0.f;
  if(kx24<24 && w<NN){
    float2 cs = ((const float2*)tab)[(kx24>>1)*NN + w];
    v = (kx24&1)? -cs.y : cs.x;
  }
  T2PK[e]=f2bu(v);
}

// Pack H-DFT twiddles: M=48 rows (j24*2+comp), K=402 (re:k<201, im:k>=201), pad 416.
// re_out = sum re*cos - im*(sgn*sin);  im_out = sum re*(sgn*sin) + im*cos;
// sgn=-1 for j24<12, +1 else; k2=(j24<12)?j24:24-j24.
__global__ void k_tpack3(const float* __restrict__ tab, unsigned short* __restrict__ T3PK){
  int e = blockIdx.x*256 + threadIdx.x;
  if(e>=19968) return;
  int idx=e>>9;                 // 0..38
  int mt=idx/13, chunk=idx-mt*13;
  int lane=(e>>3)&63, j=e&7;
  int m_=lane&15, g=lane>>4;
  int m = mt*16+m_;             // 0..47
  int k = chunk*32+g*8+j;
  float v=0.f;
  if(m<48 && k<402){
    int j24=m>>1, comp=m&1;
    int k2=(j24<12)? j24 : 24-j24;
    float sgn=(j24<12)? -1.f : 1.f;
    int h=(k<201)? k : k-201;
    float2 cs=((const float2*)tab)[k2*NN+h];
    float cc=cs.x, ss=sgn*cs.y;
    if(k<201) v = comp? ss : cc;
    else      v = comp? cc : -ss;
  }
  T3PK[e]=f2bu(v);
}

// Separable encoder tables. grid (192,2), 64 thr.
__global__ void k_pretab(const float* __restrict__ Wp, const float* __restrict__ bp,
                         float* __restrict__ Ux, float* __restrict__ Uy){
  int i = blockIdx.x;
  int ax = blockIdx.y;
  int c = threadIdx.x;
  float g = (float)i*(1.0f/191.0f);
  float acc;
  if(ax==0) acc = bp[c] + g*Wp[64+c];
  else      acc = g*Wp[128+c];
  int cosBase = (ax==0)? 3 : 4;
  int sinBase = (ax==0)? 23 : 24;
  #pragma unroll
  for(int l=0;l<10;l++){
    float f = PI_F*(float)(1<<l);
    float sv,cv;
    sincosf(g*f,&sv,&cv);
    acc += cv*Wp[(cosBase+2*l)*64+c] + sv*Wp[(sinBase+2*l)*64+c];
  }
  float* U = (ax==0)? Ux : Uy;
  U[i*64+c] = acc;
}

// Pack 16 64x64 weight matrices into bf16 MFMA-fragment order.
__global__ void k_wpack(const float* __restrict__ m1w, const float* __restrict__ m2w,
                        const float* __restrict__ ww,  const float* __restrict__ q1w,
                        unsigned short* __restrict__ WPK){
  int bx = blockIdx.x, tid = threadIdx.x;
  const float* src;
  if(bx<12){
    int l=bx/3, sel=bx-l*3;
    src = (sel==0)? m1w+(size_t)l*4096 : (sel==1)? m2w+(size_t)l*4096 : ww+(size_t)l*4096;
  } else {
    src = q1w + (size_t)(bx-12)*4096;
  }
  unsigned short* dst = WPK + (size_t)bx*4096;
  #pragma unroll
  for(int t=0;t<16;t++){
    int d = tid*16+t;
    int frag=d>>9, lane=(d>>3)&63, j=d&7;
    int mt=frag>>1, kh=frag&1, m_=lane&15, g=lane>>4;
    dst[d] = f2bu(src[(size_t)(16*mt+m_)*64 + 32*kh + 8*g + j]);
  }
}

// Transpose spectral weights for layer into WT[m][comp][io].
__global__ void __launch_bounds__(256) k_wtrans(const float* __restrict__ w1,
        const float* __restrict__ w2, float* __restrict__ WT){
  __shared__ float tile[64][65];
  int io0 = blockIdx.x*64;
  int c0  = blockIdx.y*64;
  int z   = blockIdx.z;
  const float* src = (z==0)? w1 : w2;
  int tid = threadIdx.x;
  #pragma unroll
  for(int it=0;it<16;it++){
    int e = tid + 256*it;
    int r = e>>6, c = e&63;
    if(c0+c<288) tile[r][c] = src[(size_t)(io0+r)*288 + c0 + c];
  }
  __syncthreads();
  #pragma unroll
  for(int it=0;it<16;it++){
    int e = tid + 256*it;
    int rp = e>>6, cp = e&63;
    int col = c0 + rp;
    if(col<288){
      int ky = col/24, rm = col - ky*24;
      int kx = rm>>1, comp = rm&1;
      int m = z*144 + ky*12 + kx;
      WT[(size_t)m*8192 + comp*4096 + io0 + cp] = tile[cp][rp];
    }
  }
}

// encoder: A[b][p][c] = x*Wp0[c] + Ux[hh][c] + Uy[ww][c]; zeros in pad.
__global__ void k_encoder(const float* __restrict__ x, const float* __restrict__ Wp,
                          const float* __restrict__ Ux, const float* __restrict__ Uy,
                          bf16* __restrict__ A){
  int tid=threadIdx.x;
  int p = blockIdx.x*256+tid;
  if(p>=NPIX) return;
  int b = blockIdx.y;
  uint4* dst = (uint4*)(A + ((size_t)b*NPIX + p)*64);
  int hh=p/NN, ww=p-hh*NN;
  if(hh>=SS || ww>=SS){
    uint4 z = {0,0,0,0};
    #pragma unroll
    for(int i=0;i<8;i++) dst[i]=z;
    return;
  }
  float xv = x[((size_t)b*SS+hh)*SS+ww];
  const float4* ux = (const float4*)(Ux + hh*64);
  const float4* uy = (const float4*)(Uy + ww*64);
  const float4* w0 = (const float4*)Wp;
  #pragma unroll
  for(int i=0;i<8;i++){
    float4 a0 = ux[2*i],   a1 = ux[2*i+1];
    float4 b0 = uy[2*i],   b1 = uy[2*i+1];
    float4 c0 = w0[2*i],   c1 = w0[2*i+1];
    float v0=xv*c0.x+a0.x+b0.x, v1=xv*c0.y+a0.y+b0.y;
    float v2=xv*c0.z+a0.z+b0.z, v3=xv*c0.w+a0.w+b0.w;
    float v4=xv*c1.x+a1.x+b1.x, v5=xv*c1.y+a1.y+b1.y;
    float v6=xv*c1.z+a1.z+b1.z, v7=xv*c1.w+a1.w+b1.w;
    uint4 v;
    v.x = (unsigned)f2bu(v0) | ((unsigned)f2bu(v1)<<16);
    v.y = (unsigned)f2bu(v2) | ((unsigned)f2bu(v3)<<16);
    v.z = (unsigned)f2bu(v4) | ((unsigned)f2bu(v5)<<16);
    v.w = (unsigned)f2bu(v6) | ((unsigned)f2bu(v7)<<16);
    dst[i]=v;
  }
}

// MFMA forward DFT along W. grid 402 x 4 waves; wave = one row R=b*201+h.
// Stores bf16 XWb[plane][((b*12+kx)*201+h)*64+c] (h-contiguous per (b,kx)).
__global__ void __launch_bounds__(256) k_dftw(const bf16* __restrict__ A,
        const unsigned short* __restrict__ T2PK, bf16* __restrict__ XWb){
  int tid=threadIdx.x, wid=tid>>6, l=tid&63;
  int m_=l&15, g=l>>4;
  int R = blockIdx.x*4 + wid;
  const bf16* row = A + (size_t)R*NN*64;
  f32x4 acc[2][4];
  #pragma unroll
  for(int mt=0;mt<2;mt++){
    #pragma unroll
    for(int nt=0;nt<4;nt++) acc[mt][nt]=f32x4{0.f,0.f,0.f,0.f};
  }
  for(int chunk=0;chunk<7;chunk++){
    int wbase = chunk*32 + g*8;
    s8v bf[4];
    if(chunk<6){
      #pragma unroll
      for(int nt=0;nt<4;nt++){
        s8v f;
        #pragma unroll
        for(int j=0;j<8;j++){
          unsigned short v;
          bf16 hv = row[(size_t)(wbase+j)*64 + 16*nt + m_];
          __builtin_memcpy(&v,&hv,2);
          f[j]=(short)v;
        }
        bf[nt]=f;
      }
    } else {
      #pragma unroll
      for(int nt=0;nt<4;nt++){
        s8v f;
        #pragma unroll
        for(int j=0;j<8;j++){
          unsigned short v=0;
          if(wbase+j<NN){
            bf16 hv = row[(size_t)(wbase+j)*64 + 16*nt + m_];
            __builtin_memcpy(&v,&hv,2);
          }
          f[j]=(short)v;
        }
        bf[nt]=f;
      }
    }
    #pragma unroll
    for(int mt=0;mt<2;mt++){
      s8v af = *(const s8v*)(T2PK + (size_t)(mt*7+chunk)*512 + l*8);
      #pragma unroll
      for(int nt=0;nt<4;nt++)
        acc[mt][nt]=__builtin_amdgcn_mfma_f32_16x16x32_bf16(af,bf[nt],acc[mt][nt],0,0,0);
    }
  }
  int bb = R/NN, h = R - bb*NN;
  #pragma unroll
  for(int mt=0;mt<2;mt++){
    #pragma unroll
    for(int nt=0;nt<4;nt++){
      #pragma unroll
      for(int e=0;e<4;e++){
        int kx24 = mt*16 + 4*g + e;
        if(kx24<24){
          int plane = kx24&1, kx = kx24>>1;
          XWb[(size_t)plane*XWPL + (((size_t)bb*12+kx)*201 + h)*64 + 16*nt + m_]
            = f2b(acc[mt][nt][e]);
        }
      }
    }
  }
}

// MFMA H-DFT: grid (12, BB, 2); 4 waves, wave wid<3 owns m-tile wid; z = nt-half.
// XF[(j24*12+kx)*1024 + (b*64+c)*2 + comp] from D rows m=wid*16+4g+e.
__global__ void __launch_bounds__(256) k_dfthM(const bf16* __restrict__ XWb,
        const unsigned short* __restrict__ T3PK, float* __restrict__ XF){
  int kx=blockIdx.x, b=blockIdx.y, zh=blockIdx.z;
  int tid=threadIdx.x, wid=tid>>6, l=tid&63;
  int m_=l&15, g=l>>4;
  if(wid>=3) return;
  const bf16* base = XWb + (((size_t)b*12+kx)*201)*64;
  f32x4 acc0=f32x4{0.f,0.f,0.f,0.f}, acc1=f32x4{0.f,0.f,0.f,0.f};
  for(int chunk=0;chunk<13;chunk++){
    s8v bf0, bf1;
    #pragma unroll
    for(int nt2=0;nt2<2;nt2++){
      int c = 16*(zh*2+nt2) + m_;
      s8v f;
      #pragma unroll
      for(int j=0;j<8;j++){
        int k = chunk*32 + g*8 + j;
        unsigned short v=0;
        if(k<402){
          int h = (k<201)? k : (k-201);
          size_t poff = (k<201)? 0 : (size_t)XWPL;
          bf16 hv = base[poff + (size_t)h*64 + c];
          __builtin_memcpy(&v,&hv,2);
        }
        f[j]=(short)v;
      }
      if(nt2==0) bf0=f; else bf1=f;
    }
    s8v af = *(const s8v*)(T3PK + (size_t)(wid*13+chunk)*512 + l*8);
    acc0=__builtin_amdgcn_mfma_f32_16x16x32_bf16(af,bf0,acc0,0,0,0);
    acc1=__builtin_amdgcn_mfma_f32_16x16x32_bf16(af,bf1,acc1,0,0,0);
  }
  #pragma unroll
  for(int nt2=0;nt2<2;nt2++){
    f32x4 a = (nt2==0)? acc0 : acc1;
    int c = 16*(zh*2+nt2) + m_;
    #pragma unroll
    for(int e2=0;e2<4;e2++){
      int m = wid*16 + 4*g + e2;     // 0..47
      int j24 = m>>1, comp = m&1;
      XF[(size_t)(j24*12+kx)*1024 + ((size_t)b*64+c)*2 + comp] = a[e2];
    }
  }
}

// per-mode 64x64 complex mix; ILP split accumulators.
__global__ void __launch_bounds__(512) k_modemix(const float* __restrict__ XF,
     const float* __restrict__ WT, float* __restrict__ XO){
  __shared__ float sx[1024];
  __shared__ float swr[4096], swi[4096];
  int m=blockIdx.x;
  int tid=threadIdx.x;
  sx[tid]     = XF[(size_t)m*1024+tid];
  sx[tid+512] = XF[(size_t)m*1024+tid+512];
  const float* wr = WT + (size_t)m*8192;
  const float* wi = wr + 4096;
  for(int io=tid;io<4096;io+=512){
    swr[io]=wr[io];
    swi[io]=wi[io];
  }
  __syncthreads();
  int b=tid>>6, o=tid&63;
  const float* xb = sx + b*128;
  float re0=0.f,re1=0.f,im0=0.f,im1=0.f;
  #pragma unroll 8
  for(int i=0;i<64;i+=2){
    float a=xb[2*i], b2=xb[2*i+1];
    float c=swr[i*64+o], d=swi[i*64+o];
    re0 = fmaf(a,c, fmaf(-b2,d, re0));
    im0 = fmaf(a,d, fmaf( b2,c, im0));
    float a1=xb[2*i+2], b3=xb[2*i+3];
    float c1=swr[(i+1)*64+o], d1=swi[(i+1)*64+o];
    re1 = fmaf(a1,c1, fmaf(-b3,d1, re1));
    im1 = fmaf(a1,d1, fmaf( b3,c1, im1));
  }
  XO[2*((size_t)m*512+tid)]  =re0+re1;
  XO[2*((size_t)m*512+tid)+1]=im0+im1;
}

// Merged inverse: per row R, idfth into LDS (factors folded), then the C2R
// along W as MFMA: C[w][o] = sum_k24 T[w][k24]*Y24[k24][o], T prepacked (TPK).
__global__ void __launch_bounds__(256) k_ispec(const float* __restrict__ XO,
        const float* __restrict__ tab, const unsigned short* __restrict__ TPK,
        bf16* __restrict__ C){
  __shared__ float2 yl[12][64];
  __shared__ float2 cs13[13];
  int R=blockIdx.x;
  int b=R/NN, h=R-b*NN;
  int tid=threadIdx.x;
  if(tid<13) cs13[tid]=((const float2*)tab)[tid*NN+h];
  __syncthreads();
  const float sc = 1.0f/40401.0f;
  #pragma unroll
  for(int it=0;it<3;it++){
    int item = tid + 256*it;
    int kx = item>>6, o = item&63;
    float re0=0.f,im0=0.f,re1=0.f,im1=0.f;
    #pragma unroll
    for(int j=0;j<24;j+=2){
      {
        int k2=(j<12)?j:24-j;
        float sgn=(j<12)?1.0f:-1.0f;
        float2 xo = *(const float2*)(XO + 2*(((size_t)(j*12+kx)*512) + b*64 + o));
        float2 cs = cs13[k2];
        float cc=cs.x, s2=sgn*cs.y;
        re0 = fmaf(xo.x,cc, fmaf(-xo.y,s2, re0));
        im0 = fmaf(xo.x,s2, fmaf( xo.y,cc, im0));
      }
      {
        int j1=j+1;
        int k2=(j1<12)?j1:24-j1;
        float sgn=(j1<12)?1.0f:-1.0f;
        float2 xo = *(const float2*)(XO + 2*(((size_t)(j1*12+kx)*512) + b*64 + o));
        float2 cs = cs13[k2];
        float cc=cs.x, s2=sgn*cs.y;
        re1 = fmaf(xo.x,cc, fmaf(-xo.y,s2, re1));
        im1 = fmaf(xo.x,s2, fmaf( xo.y,cc, im1));
      }
    }
    float fr = (kx==0)? sc : 2.0f*sc;
    float fi = (kx==0)? sc : -2.0f*sc;
    yl[kx][o] = float2{ (re0+re1)*fr, (im0+im1)*fi };
  }
  __syncthreads();
  int wid=tid>>6, l=tid&63, m_=l&15, g=l>>4;
  int o = wid*16 + m_;
  s8v bfr;
  #pragma unroll
  for(int j=0;j<4;j++){
    float2 v = yl[4*g+j][o];
    bfr[2*j]   = (short)f2bu(v.x);
    bfr[2*j+1] = (short)f2bu(v.y);
  }
  bf16* cp = C + (size_t)R*NN*64;
  #pragma unroll
  for(int wt=0; wt<13; wt++){
    s8v af = *(const s8v*)(TPK + (size_t)wt*512 + l*8);
    f32x4 acc = f32x4{0.f,0.f,0.f,0.f};
    acc = __builtin_amdgcn_mfma_f32_16x16x32_bf16(af, bfr, acc, 0,0,0);
    #pragma unroll
    for(int e=0;e<4;e++){
      int w = wt*16 + 4*g + e;
      if(w<NN) cp[(size_t)w*64 + o] = f2b(acc[e]);
    }
  }
}

// Chunked Parseval Gram from XO: grid (9, BB). Block = 64-feature chunk.
__global__ void __launch_bounds__(256) k_gramC(const float* __restrict__ XO,
        float* __restrict__ GCp, float* __restrict__ SC){
  __shared__ unsigned short V[64][72];
  int chunk=blockIdx.x, b=blockIdx.y, tid=threadIdx.x;
  const float s1=1.0f/201.0f;
  const float r2=0.70710678118f;
  const float q2=1.41421356237f;
  #pragma unroll
  for(int it=0;it<16;it++){
    int e = tid + it*256;
    int fl=e>>6, ch=e&63;
    int f = chunk*64 + fl;
    int base = b*64+ch;
    float v=0.f;
    if(f<528){
      int comp=f&1, kxm=f>>1;
      int kx0=kxm/24;
      int kx=1+kx0, m=kxm-kx0*24;
      v = q2*XO[2*((size_t)(m*12+kx)*512 + base)+comp];
    } else if(f==528){
      v = XO[2*(size_t)base];
    } else if(f<551){
      int q=f-529; int mm=1+(q>>1);
      const float* p1 = XO + 2*((size_t)(mm*12)*512 + base);
      const float* p2 = XO + 2*((size_t)((24-mm)*12)*512 + base);
      v = ((q&1)==0)? r2*(p1[0]+p2[0]) : r2*(p1[1]-p2[1]);
    } else if(f==551){
      v = r2*XO[2*((size_t)(144)*512 + base)];
    } else if(f==552){
      v = r2*XO[2*((size_t)(144)*512 + base)+1];
    }
    V[ch][fl]=f2bu(v*s1);
  }
  __syncthreads();
  int wid=tid>>6, l=tid&63, m_=l&15, g=l>>4;
  f32x4 acc[4];
  #pragma unroll
  for(int mt=0;mt<4;mt++) acc[mt]=f32x4{0.f,0.f,0.f,0.f};
  #pragma unroll
  for(int kc=0;kc<2;kc++){
    s8v bfr = *(const s8v*)&V[16*wid+m_][kc*32+8*g];
    #pragma unroll
    for(int mt=0;mt<4;mt++){
      s8v afr = *(const s8v*)&V[16*mt+m_][kc*32+8*g];
      acc[mt]=__builtin_amdgcn_mfma_f32_16x16x32_bf16(afr,bfr,acc[mt],0,0,0);
    }
  }
  float* gb = GCp + ((size_t)(b*9+chunk))*4096;
  #pragma unroll
  for(int mt=0;mt<4;mt++){
    #pragma unroll
    for(int e=0;e<4;e++)
      gb[(size_t)(16*mt+4*g+e)*64 + 16*wid + m_] = acc[mt][e];
  }
  if(chunk==0 && tid<64) SC[b*64+tid] = XO[2*(size_t)(b*64+tid)];
}

// MFMA Gram v2: fragments loaded directly from global. grid (nblkx, BB) x 4 waves.
__global__ void __launch_bounds__(256) k_gramp(const bf16* __restrict__ X,
        float* __restrict__ Gpart, float* __restrict__ Spart, int HR, int WR){
  int b = blockIdx.y, blk = blockIdx.x;
  int npix = HR*WR;
  int tid=threadIdx.x, wid=tid>>6, l=tid&63;
  int m_=l&15, g=l>>4;
  int slab = blk*4 + wid;
  const bf16* xb = X + (size_t)b*NPIX*64;
  f32x4 acc[4][4];
  #pragma unroll
  for(int mt=0;mt<4;mt++){
    #pragma unroll
    for(int nt=0;nt<4;nt++) acc[mt][nt]=f32x4{0.f,0.f,0.f,0.f};
  }
  float cs[4]={0.f,0.f,0.f,0.f};
  for(int kc=0;kc<16;kc++){
    int pbase = slab*512 + kc*32 + g*8;
    int hh0=0, ww0=0;
    if(WR!=NN){ hh0 = pbase/WR; ww0 = pbase - hh0*WR; }
    const bf16* ptr[8];
    #pragma unroll
    for(int jj=0;jj<8;jj++){
      int p = pbase + jj;
      int gp;
      if(WR==NN) gp = p;
      else {
        int ww2 = ww0 + jj;
        int hh  = hh0;
        if(ww2>=WR){ ww2-=WR; hh++; }
        gp = hh*NN + ww2;
      }
      ptr[jj] = (p<npix) ? (xb + (size_t)gp*64) : (const bf16*)0;
    }
    s8v fr[4];
    #pragma unroll
    for(int t=0;t<4;t++){
      s8v f;
      float s=0.f;
      #pragma unroll
      for(int jj=0;jj<8;jj++){
        unsigned short v=0;
        if(ptr[jj]){ bf16 hv = ptr[jj][16*t+m_]; __builtin_memcpy(&v,&hv,2); }
        f[jj]=(short)v;
        s += bu2f(v);
      }
      fr[t]=f;
      cs[t]+=s;
    }
    #pragma unroll
    for(int nt=0;nt<4;nt++){
      #pragma unroll
      for(int mt=0;mt<4;mt++)
        acc[mt][nt]=__builtin_amdgcn_mfma_f32_16x16x32_bf16(fr[mt],fr[nt],acc[mt][nt],0,0,0);
    }
  }
  float* gp_ = Gpart + ((size_t)(b*GNB + slab))*4096;
  #pragma unroll
  for(int mt=0;mt<4;mt++){
    #pragma unroll
    for(int nt=0;nt<4;nt++){
      #pragma unroll
      for(int e=0;e<4;e++)
        gp_[(size_t)(16*mt + 4*g + e)*64 + 16*nt + m_] = acc[mt][nt][e];
    }
  }
  #pragma unroll
  for(int t=0;t<4;t++){
    float s=cs[t];
    s += __shfl_xor(s,16,64);
    s += __shfl_xor(s,32,64);
    if(g==0) Spart[((size_t)(b*GNB+slab))*64 + 16*t + m_] = s;
  }
}

// Parallel slab reduce: grid (16, BB). Gfin[b][4096], Sfin[b][64].
__global__ void __launch_bounds__(256) k_gramr(const float* __restrict__ Gpart,
        const float* __restrict__ Spart, float* __restrict__ Gfin,
        float* __restrict__ Sfin, int nblk){
  int b = blockIdx.y;
  int idx = blockIdx.x*256 + threadIdx.x;
  float s0=0.f,s1=0.f,s2=0.f,s3=0.f;
  int k=0;
  for(;k+3<nblk;k+=4){
    s0 += Gpart[((size_t)b*GNB + k  )*4096 + idx];
    s1 += Gpart[((size_t)b*GNB + k+1)*4096 + idx];
    s2 += Gpart[((size_t)b*GNB + k+2)*4096 + idx];
    s3 += Gpart[((size_t)b*GNB + k+3)*4096 + idx];
  }
  for(;k<nblk;k++) s0 += Gpart[((size_t)b*GNB + k)*4096 + idx];
  Gfin[(size_t)b*4096 + idx] = (s0+s1)+(s2+s3);
  if(blockIdx.x==0 && threadIdx.x<64){
    float ss=0.f;
    for(int j=0;j<nblk;j++) ss += Spart[((size_t)b*GNB + j)*64 + threadIdx.x];
    Sfin[b*64 + threadIdx.x]=ss;
  }
}

// Stats for layer (grid 32): zb2 = zb*2+grp. zb<8 -> Cb (chunked GCp + SC);
// zb>=8 -> A (Gfin/Sfin). Block = one GN group of 32 rows; i split 8-ways.
__global__ void __launch_bounds__(256) k_statsA(
        const float* __restrict__ GCp, const float* __restrict__ SC,
        const float* __restrict__ Gfin, const float* __restrict__ Sfin,
        const float* __restrict__ m1wl, const float* __restrict__ m1bl,
        const float* __restrict__ wwl,  const float* __restrict__ wbl,
        float* __restrict__ TSTAT, float* __restrict__ USTAT){
  __shared__ float Gs[4096];
  __shared__ float Ss[64];
  __shared__ float rs[256], rq[256];
  int zb2=blockIdx.x;
  int zb=zb2>>1, grp=zb2&1;
  int t=threadIdx.x;
  if(zb<8){
    #pragma unroll
    for(int e=0;e<16;e++){
      float s=0.f;
      #pragma unroll
      for(int q=0;q<9;q++) s += GCp[((size_t)(zb*9+q))*4096 + t*16+e];
      Gs[t*16+e]=s;
    }
    if(t<64) Ss[t]=SC[zb*64+t];
  } else {
    const float* GS = Gfin + (size_t)(zb-8)*4096;
    #pragma unroll
    for(int e=0;e<16;e++) Gs[t*16+e]=GS[t*16+e];
    if(t<64) Ss[t]=Sfin[(zb-8)*64+t];
  }
  __syncthreads();
  const float* W    = (zb<8)? m1wl : wwl;
  const float* bias = (zb<8)? m1bl : wbl;
  float* stat       = (zb<8)? TSTAT : USTAT;
  int b = (zb<8)? zb : zb-8;
  int o = grp*32 + (t&31);
  int sl = t>>5;                 // 8 segments of 8 i-rows
  float w[64];
  #pragma unroll
  for(int j2=0;j2<64;j2++) w[j2]=bu2f(f2bu(W[(size_t)o*64+j2]));
  const float* Gr = Gs + (size_t)(sl*8)*64;
  float quad=0.f;
  #pragma unroll
  for(int r=0;r<8;r++){
    const float* gr = Gr + r*64;
    float tt=0.f;
    #pragma unroll
    for(int j2=0;j2<64;j2++) tt += gr[j2]*w[j2];
    quad += w[sl*8+r]*tt;
  }
  float sm=0.f, sq=quad;
  if(sl==0){
    float dot=0.f;
    #pragma unroll
    for(int j2=0;j2<64;j2++) dot += w[j2]*Ss[j2];
    float bo = bias[o];
    float Nf = (float)NPIX;
    sm = dot + Nf*bo;
    sq += 2.f*bo*dot + Nf*bo*bo;
  }
  rs[t]=sm; rq[t]=sq;
  __syncthreads();
  if(t<32){
    float s2=0.f,q2=0.f;
    #pragma unroll
    for(int k=0;k<8;k++){ s2+=rs[t+32*k]; q2+=rq[t+32*k]; }
    for(int off=16;off>0;off>>=1){
      s2 += __shfl_down(s2,off,32);
      q2 += __shfl_down(q2,off,32);
    }
    if(t==0){
      float invN = 1.f/((float)NPIX*32.f);
      float mean = s2*invN;
      float var = q2*invN - mean*mean;
      stat[b*4+grp*2]   = mean;
      stat[b*4+grp*2+1] = rsqrtf(fmaxf(var,0.f)+1e-5f);
    }
  }
}

// Head stats partials: grid (BB, 4). Block = 64 rows; i split 4-ways.
__global__ void __launch_bounds__(256) k_statsQ(const float* __restrict__ Gfin,
        const float* __restrict__ Sfin,
        const float* __restrict__ W, const float* __restrict__ bias,
        float* __restrict__ QP){
  __shared__ float Gs[4096];
  __shared__ float Ss[64];
  __shared__ float rs[256], rq[256];
  int b=blockIdx.x, z=blockIdx.y, t=threadIdx.x;
  #pragma unroll
  for(int e=0;e<16;e++) Gs[t*16+e]=Gfin[(size_t)b*4096 + t*16+e];
  if(t<64) Ss[t]=Sfin[b*64+t];
  __syncthreads();
  int o = z*64 + (t&63);
  int sl = t>>6;
  float w[64];
  #pragma unroll
  for(int j2=0;j2<64;j2++) w[j2]=bu2f(f2bu(W[(size_t)o*64+j2]));
  const float* Gr = Gs + (size_t)(sl*16)*64;
  float quad=0.f;
  #pragma unroll
  for(int r=0;r<16;r++){
    const float* gr = Gr + r*64;
    float tt=0.f;
    #pragma unroll
    for(int j2=0;j2<64;j2++) tt += gr[j2]*w[j2];
    quad += w[sl*16+r]*tt;
  }
  float sm=0.f, sq=quad;
  if(sl==0){
    float dot=0.f;
    #pragma unroll
    for(int j2=0;j2<64;j2++) dot += w[j2]*Ss[j2];
    float bo=bias[o];
    float Nf=(float)QPIX;
    sm = dot + Nf*bo;
    sq += 2.f*bo*dot + Nf*bo*bo;
  }
  rs[t]=sm; rq[t]=sq;
  __syncthreads();
  if(t<64){
    float s2 = rs[t]+rs[t+64]+rs[t+128]+rs[t+192];
    float q2 = rq[t]+rq[t+64]+rq[t+128]+rq[t+192];
    for(int off=32;off>0;off>>=1){
      s2 += __shfl_down(s2,off,64);
      q2 += __shfl_down(q2,off,64);
    }
    if(t==0){
      int g = z>>1;
      atomicAdd(&QP[b*4+g*2],   s2);
      atomicAdd(&QP[b*4+g*2+1], q2);
    }
  }
}

// Finalize head stats. grid 1, 16 threads.
__global__ void k_qfin(const float* __restrict__ QP, float* __restrict__ QSTAT){
  int t=threadIdx.x;
  if(t>=16) return;
  int b=t>>1, g=t&1;
  float s=QP[b*4+g*2], ss=QP[b*4+g*2+1];
  float invN=1.f/((float)QPIX*128.f);
  float mean=s*invN, var=ss*invN-mean*mean;
  QSTAT[b*4+g*2]   = mean;
  QSTAT[b*4+g*2+1] = rsqrtf(fmaxf(var,0.f)+1e-5f);
}

// MFMA fused layer with packed weights; GN affine folded to single fma.
__global__ void __launch_bounds__(256) k_fuse(const bf16* __restrict__ Cb,
    bf16* __restrict__ A,
    const unsigned short* __restrict__ wp1, const float* __restrict__ m1b,
    const float* __restrict__ mg,  const float* __restrict__ mbt,
    const unsigned short* __restrict__ wp2, const float* __restrict__ m2b,
    const unsigned short* __restrict__ wpw, const float* __restrict__ wbk,
    const float* __restrict__ ng,  const float* __restrict__ nb,
    const float* __restrict__ tstat, const float* __restrict__ ustat, int last){
  __shared__ unsigned short vlds[4][64][72];
  int tid=threadIdx.x;
  int wid=tid>>6, l=tid&63;
  int m_=l&15, g=l>>4;
  int b=blockIdx.y;
  int p0=blockIdx.x*256 + wid*64;
  const bf16* cbb = Cb + (size_t)b*NPIX*64;
  const bf16* ab  = A  + (size_t)b*NPIX*64;

  s8v af[4][2];
  f32x4 acc[4][4];

  #pragma unroll
  for(int mt=0;mt<4;mt++){
    #pragma unroll
    for(int kh=0;kh<2;kh++)
      af[mt][kh]=*(const s8v*)(wp1 + (mt*2+kh)*512 + l*8);
    float4 b4 = *(const float4*)(m1b + 16*mt + 4*g);
    #pragma unroll
    for(int nt=0;nt<4;nt++) acc[mt][nt]=f32x4{b4.x,b4.y,b4.z,b4.w};
  }
  #pragma unroll
  for(int nt=0;nt<4;nt++){
    int p = p0 + 16*nt + m_;
    int pc = p<NPIX? p : NPIX-1;
    const s8v* xb = (const s8v*)(cbb + (size_t)pc*64);
    s8v b0 = xb[g], b1 = xb[4+g];
    #pragma unroll
    for(int mt=0;mt<4;mt++){
      acc[mt][nt]=__builtin_amdgcn_mfma_f32_16x16x32_bf16(af[mt][0],b0,acc[mt][nt],0,0,0);
      acc[mt][nt]=__builtin_amdgcn_mfma_f32_16x16x32_bf16(af[mt][1],b1,acc[mt][nt],0,0,0);
    }
  }
  {
    float tm0=tstat[b*4],tr0=tstat[b*4+1],tm1=tstat[b*4+2],tr1=tstat[b*4+3];
    #pragma unroll
    for(int mt=0;mt<4;mt++){
      float4 g4 = *(const float4*)(mg  + 16*mt + 4*g);
      float4 t4 = *(const float4*)(mbt + 16*mt + 4*g);
      float mn = (mt<2)? tm0 : tm1;
      float rs = (mt<2)? tr0 : tr1;
      float ax=rs*g4.x, ay=rs*g4.y, az=rs*g4.z, aw=rs*g4.w;
      float cx=t4.x-mn*ax, cy=t4.y-mn*ay, cz=t4.z-mn*az, cw=t4.w-mn*aw;
      #pragma unroll
      for(int nt=0;nt<4;nt++){
        int pl = 16*nt + m_;
        f32x4 t = acc[mt][nt];
        float v0 = gelu_f(fmaf(t[0],ax,cx));
        float v1 = gelu_f(fmaf(t[1],ay,cy));
        float v2 = gelu_f(fmaf(t[2],az,cz));
        float v3 = gelu_f(fmaf(t[3],aw,cw));
        uint2 pk;
        pk.x = (unsigned)f2bu(v0) | ((unsigned)f2bu(v1)<<16);
        pk.y = (unsigned)f2bu(v2) | ((unsigned)f2bu(v3)<<16);
        *(uint2*)&vlds[wid][pl][16*mt+4*g] = pk;
      }
    }
  }
  __syncthreads();
  #pragma unroll
  for(int mt=0;mt<4;mt++){
    #pragma unroll
    for(int kh=0;kh<2;kh++)
      af[mt][kh]=*(const s8v*)(wpw + (mt*2+kh)*512 + l*8);
    float4 b4 = *(const float4*)(wbk + 16*mt + 4*g);
    #pragma unroll
    for(int nt=0;nt<4;nt++) acc[mt][nt]=f32x4{b4.x,b4.y,b4.z,b4.w};
  }
  #pragma unroll
  for(int nt=0;nt<4;nt++){
    int p = p0 + 16*nt + m_;
    int pc = p<NPIX? p : NPIX-1;
    const s8v* xb = (const s8v*)(ab + (size_t)pc*64);
    s8v b0 = xb[g], b1 = xb[4+g];
    #pragma unroll
    for(int mt=0;mt<4;mt++){
      acc[mt][nt]=__builtin_amdgcn_mfma_f32_16x16x32_bf16(af[mt][0],b0,acc[mt][nt],0,0,0);
      acc[mt][nt]=__builtin_amdgcn_mfma_f32_16x16x32_bf16(af[mt][1],b1,acc[mt][nt],0,0,0);
    }
  }
  {
    float um0=ustat[b*4],ur0=ustat[b*4+1],um1=ustat[b*4+2],ur1=ustat[b*4+3];
    #pragma unroll
    for(int mt=0;mt<4;mt++){
      float4 n4 = *(const float4*)(ng  + 16*mt + 4*g);
      float4 nb4= *(const float4*)(nb  + 16*mt + 4*g);
      float4 m24= *(const float4*)(m2b + 16*mt + 4*g);
      float mn = (mt<2)? um0 : um1;
      float rs = (mt<2)? ur0 : ur1;
      float ax=rs*n4.x, ay=rs*n4.y, az=rs*n4.z, aw=rs*n4.w;
      float cx=m24.x+nb4.x-mn*ax, cy=m24.y+nb4.y-mn*ay;
      float cz=m24.z+nb4.z-mn*az, cw=m24.w+nb4.w-mn*aw;
      #pragma unroll
      for(int nt=0;nt<4;nt++){
        f32x4 u = acc[mt][nt];
        u[0] = fmaf(u[0],ax,cx);
        u[1] = fmaf(u[1],ay,cy);
        u[2] = fmaf(u[2],az,cz);
        u[3] = fmaf(u[3],aw,cw);
        acc[mt][nt]=u;
      }
    }
  }
  #pragma unroll
  for(int mt=0;mt<4;mt++){
    #pragma unroll
    for(int kh=0;kh<2;kh++)
      af[mt][kh]=*(const s8v*)(wp2 + (mt*2+kh)*512 + l*8);
  }
  #pragma unroll
  for(int nt=0;nt<4;nt++){
    int pl = 16*nt + m_;
    const s8v* vp = (const s8v*)&vlds[wid][pl][0];
    s8v b0 = vp[g], b1 = vp[4+g];
    #pragma unroll
    for(int mt=0;mt<4;mt++){
      acc[mt][nt]=__builtin_amdgcn_mfma_f32_16x16x32_bf16(af[mt][0],b0,acc[mt][nt],0,0,0);
      acc[mt][nt]=__builtin_amdgcn_mfma_f32_16x16x32_bf16(af[mt][1],b1,acc[mt][nt],0,0,0);
    }
  }
  #pragma unroll
  for(int nt=0;nt<4;nt++){
    int p = p0 + 16*nt + m_;
    if(p>=NPIX) continue;
    bf16* dp = A + ((size_t)b*NPIX + p)*64;
    #pragma unroll
    for(int mt=0;mt<4;mt++){
      f32x4 h = acc[mt][nt];
      float h0=h[0],h1=h[1],h2=h[2],h3=h[3];
      if(!last){ h0=gelu_f(h0); h1=gelu_f(h1); h2=gelu_f(h2); h3=gelu_f(h3); }
      uint2 pk;
      pk.x = (unsigned)f2bu(h0) | ((unsigned)f2bu(h1)<<16);
      pk.y = (unsigned)f2bu(h2) | ((unsigned)f2bu(h3)<<16);
      *(uint2*)(dp + 16*mt + 4*g) = pk;
    }
  }
}

// Head: 128px/block (grid 288,BB); wave = one oc chunk over 8 nt; folded GN coeffs.
__global__ void __launch_bounds__(256) k_qout(const bf16* __restrict__ A,
    const unsigned short* __restrict__ qpack, const float* __restrict__ q1b,
    const float* __restrict__ qg, const float* __restrict__ qbt,
    const float* __restrict__ q2w, const float* __restrict__ q2b,
    const float* __restrict__ qstat, float* __restrict__ out){
  __shared__ unsigned short xq[128][72];
  __shared__ float part[4][128];
  int tid=threadIdx.x;
  int wid=tid>>6, l=tid&63;
  int m_=l&15, g=l>>4;
  int b=blockIdx.y;
  int px0=blockIdx.x*128;
  {
    int p = px0 + (tid>>1);
    int half = tid&1;
    int hh=p/SS, ww2=p-hh*SS;
    const uint4* src=(const uint4*)(A + (((size_t)b*NPIX) + (size_t)hh*NN + ww2)*64 + half*32);
    uint4* drow=(uint4*)&xq[tid>>1][half*32];
    #pragma unroll
    for(int i=0;i<4;i++) drow[i]=src[i];
  }
  __syncthreads();
  int oc=wid;
  const unsigned short* wp = qpack + (size_t)oc*4096;
  s8v af[4][2];
  f32x4 bi4[4];
  float4 a4[4], c4[4], w4[4];
  float m0=qstat[b*4],r0=qstat[b*4+1],m1=qstat[b*4+2],r1=qstat[b*4+3];
  float mn=(oc<2)?m0:m1, rs=(oc<2)?r0:r1;
  #pragma unroll
  for(int mt=0;mt<4;mt++){
    #pragma unroll
    for(int kh=0;kh<2;kh++)
      af[mt][kh]=*(const s8v*)(wp + (mt*2+kh)*512 + l*8);
    float4 b4=*(const float4*)(q1b + 64*oc + 16*mt + 4*g);
    bi4[mt]=f32x4{b4.x,b4.y,b4.z,b4.w};
    float4 g4=*(const float4*)(qg  + 64*oc + 16*mt + 4*g);
    float4 t4=*(const float4*)(qbt + 64*oc + 16*mt + 4*g);
    w4[mt]=*(const float4*)(q2w + 64*oc + 16*mt + 4*g);
    a4[mt]=float4{rs*g4.x, rs*g4.y, rs*g4.z, rs*g4.w};
    c4[mt]=float4{t4.x-mn*a4[mt].x, t4.y-mn*a4[mt].y, t4.z-mn*a4[mt].z, t4.w-mn*a4[mt].w};
  }
  #pragma unroll
  for(int nt=0;nt<8;nt++){
    const s8v* vp = (const s8v*)&xq[16*nt+m_][0];
    s8v b0=vp[g], b1=vp[4+g];
    f32x4 acc[4];
    #pragma unroll
    for(int mt=0;mt<4;mt++) acc[mt]=bi4[mt];
    #pragma unroll
    for(int mt=0;mt<4;mt++){
      acc[mt]=__builtin_amdgcn_mfma_f32_16x16x32_bf16(af[mt][0],b0,acc[mt],0,0,0);
      acc[mt]=__builtin_amdgcn_mfma_f32_16x16x32_bf16(af[mt][1],b1,acc[mt],0,0,0);
    }
    float pp=0.f;
    #pragma unroll
    for(int mt=0;mt<4;mt++){
      f32x4 t=acc[mt];
      pp += gelu_f(fmaf(t[0],a4[mt].x,c4[mt].x))*w4[mt].x;
      pp += gelu_f(fmaf(t[1],a4[mt].y,c4[mt].y))*w4[mt].y;
      pp += gelu_f(fmaf(t[2],a4[mt].z,c4[mt].z))*w4[mt].z;
      pp += gelu_f(fmaf(t[3],a4[mt].w,c4[mt].w))*w4[mt].w;
    }
    pp += __shfl_xor(pp,16,64);
    pp += __shfl_xor(pp,32,64);
    if(g==0) part[wid][16*nt+m_]=pp;
  }
  __syncthreads();
  if(tid<128)
    out[(size_t)b*QPIX + px0 + tid] =
        q2b[0] + part[0][tid]+part[1][tid]+part[2][tid]+part[3][tid];
}

extern "C" void kernel_launch(void* const* d_in, const int* in_sizes, int n_in,
                              void* d_out, int out_size, void* d_ws, size_t ws_size,
                              hipStream_t stream){
  const float* x   = (const float*)d_in[0];
  const float* Wp  = (const float*)d_in[1];
  const float* bp  = (const float*)d_in[2];
  const float* sw1 = (const float*)d_in[3];
  const float* sw2 = (const float*)d_in[4];
  const float* m1w = (const float*)d_in[5];
  const float* m1b = (const float*)d_in[6];
  const float* mg  = (const float*)d_in[7];
  const float* mbt = (const float*)d_in[8];
  const float* m2w = (const float*)d_in[9];
  const float* m2b = (const float*)d_in[10];
  const float* ww  = (const float*)d_in[11];
  const float* wb  = (const float*)d_in[12];
  const float* ng  = (const float*)d_in[13];
  const float* nb  = (const float*)d_in[14];
  const float* q1w = (const float*)d_in[15];
  const float* q1b = (const float*)d_in[16];
  const float* qg  = (const float*)d_in[17];
  const float* qbt = (const float*)d_in[18];
  const float* q2w = (const float*)d_in[19];
  const float* q2b = (const float*)d_in[20];
  float* out = (float*)d_out;

  char* w8 = (char*)d_ws;
  const size_t ACT_B = (size_t)64*BB*NPIX*sizeof(bf16);   // 41,370,624
  bf16*  A    = (bf16*)(w8);
  bf16*  Cb   = (bf16*)(w8 + ACT_B);
  float* SPEC = (float*)(w8 + 2*ACT_B);                    // XWb / WT / Gpart overlays
  float* XF   = (float*)(w8 + 2*ACT_B + 9879552);
  float* XO   = (float*)(w8 + 2*ACT_B + 9879552 + 1179648);
  float* TB   = (float*)(w8 + 2*ACT_B + 9879552 + 2*1179648);
  char*  g8   = w8 + 2*ACT_B + 9879552 + 2*1179648 + 20992;
  float* TSTAT= (float*)g8;
  float* USTAT= TSTAT + 32;
  float* QSTAT= USTAT + 32;
  float* UxT  = QSTAT + 32;                  // 192*64
  float* UyT  = UxT + 12288;                 // 192*64
  unsigned short* WPK = (unsigned short*)(UyT + 12288);   // 16*4096 bf16
  float* GFIN = (float*)(WPK + 16*4096);     // 8*4096 (reduced bypass gram)
  float* SFIN = GFIN + 8*4096;               // 8*64
  float* SC   = SFIN + 8*64;                 // 8*64 (Parseval col sums)
  unsigned short* TPK = (unsigned short*)(SC + 8*64);     // 13*512 inverse twiddles
  unsigned short* T2PK = TPK + 6656;                      // 14*512 forward twiddles
  unsigned short* T3PK = T2PK + 7168;                     // 39*512 H-DFT twiddles
  float* QP   = (float*)(T3PK + 19968);      // 32 (head stat partials)
  float* GCp  = QP + 32;                     // 8*9*4096 (dedicated Parseval partials)
  bf16*  XWb  = (bf16*)SPEC;                 // 2*XWPL bf16 = 4.94MB (SPEC overlay)
  float* Gpart = SPEC;                       // 8*80*4096 fl = 10.49MB <= SPEC+XF
  float* Spart = Gpart + (size_t)8*GNB*4096;
  float* WT = SPEC;                          // 288*8192 floats = 9.44MB
  size_t needed = (size_t)(2*ACT_B) + 9879552 + 2*1179648 + 20992
                + 3*32*4 + 2*12288*4 + 16*4096*2 + (8*4096+2*8*64)*4
                + 13312 + 14336 + 39936 + 128 + (size_t)8*9*4096*4;
  if(ws_size < needed) return;

  k_tab<<<11,256,0,stream>>>(TB);
  k_tpack<<<26,256,0,stream>>>(TB, TPK);
  k_tpack2<<<28,256,0,stream>>>(TB, T2PK);
  k_tpack3<<<78,256,0,stream>>>(TB, T3PK);
  k_pretab<<<dim3(192,2),64,0,stream>>>(Wp, bp, UxT, UyT);
  k_wpack<<<16,256,0,stream>>>(m1w, m2w, ww, q1w, WPK);
  k_encoder<<<dim3(158,BB),256,0,stream>>>(x, Wp, UxT, UyT, A);

  for(int l=0;l<4;l++){
    const float* sw1l = sw1 + (size_t)l*1179648;
    const float* sw2l = sw2 + (size_t)l*1179648;
    k_dftw<<<402,256,0,stream>>>(A, T2PK, XWb);
    k_dfthM<<<dim3(12,BB,2),256,0,stream>>>(XWb, T3PK, XF);
    k_wtrans<<<dim3(64,5,2),256,0,stream>>>(sw1l, sw2l, WT);
    k_modemix<<<288,512,0,stream>>>(XF, WT, XO);
    k_ispec<<<1608,256,0,stream>>>(XO, TB, TPK, Cb);
    k_gramC<<<dim3(9,BB),256,0,stream>>>(XO, GCp, SC);
    k_gramp<<<dim3(20,BB),256,0,stream>>>(A, Gpart, Spart, NN, NN);
    k_gramr<<<dim3(16,BB),256,0,stream>>>(Gpart, Spart, GFIN, SFIN, 80);
    k_statsA<<<32,256,0,stream>>>(GCp, SC, GFIN, SFIN,
          m1w + (size_t)l*4096, m1b + l*64, ww + (size_t)l*4096, wb + l*64,
          TSTAT, USTAT);
    k_fuse<<<dim3(158,BB),256,0,stream>>>(Cb, A,
          WPK + (size_t)(l*3+0)*4096, m1b + l*64, mg + l*64, mbt + l*64,
          WPK + (size_t)(l*3+1)*4096, m2b + l*64,
          WPK + (size_t)(l*3+2)*4096, wb  + l*64, ng + l*64, nb + l*64,
          TSTAT, USTAT, (l==3)?1:0);
  }

  k_gramp<<<dim3(18,BB),256,0,stream>>>(A, Gpart, Spart, SS, SS);
  k_gramr<<<dim3(16,BB),256,0,stream>>>(Gpart, Spart, GFIN, SFIN, 72);
  hipMemsetAsync(QP, 0, 32*sizeof(float), stream);
  k_statsQ<<<dim3(BB,4),256,0,stream>>>(GFIN, SFIN, q1w, q1b, QP);
  k_qfin<<<1,16,0,stream>>>(QP, QSTAT);
  k_qout<<<dim3(288,BB),256,0,stream>>>(A, WPK + (size_t)12*4096, q1b,
          qg, qbt, q2w, q2b, QSTAT, out);
}

// Round 21
// 820.481 us; speedup vs baseline: 2.6840x; 1.0210x over previous
//
#include <hip/hip_runtime.h>
#include <hip/hip_bf16.h>
#include <math.h>

// FNO2d: B=8, S=192, pad->201x201, C=64, modes 12x12, 4 layers.
// Pixel-major activations [b][p][c]; MFMA conv GEMMs; MFMA forward-W (dftw),
// MFMA H-DFT (dfthM), MFMA inverse-W (ispec); chunked Parseval Gram;
// MFMA bypass Gram v2; fast sigmoid-gelu; barrier-free 2-wave k_fuse;
// bf16 spectral weights (WT).

#define NN 201
#define SS 192
#define NPIX 40401
#define QPIX 36864
#define BB 8
#define GNB 80           // gram slabs per b, 512 px each (one slab per wave)
#define XWPL 1234944     // 1608*12*64 (per-plane element stride; bf16)
#define PI_F 3.14159265358979323846f

typedef __hip_bfloat16 bf16;
typedef __attribute__((ext_vector_type(8))) short s8v;
typedef __attribute__((ext_vector_type(4))) float f32x4;

// tanh-form gelu via sigmoid: x*sigma(1.5957691x + 0.0713548x^3); |err| <= ~1e-3
__device__ __forceinline__ float gelu_f(float x){
  float x2 = x*x;
  float t  = fmaf(x2, 0.0713548162f, 1.5957691216f);
  float e  = __expf(-x*t);
  return x*__builtin_amdgcn_rcpf(1.0f+e);
}
__device__ __forceinline__ float b2f(bf16 v){ return __bfloat162float(v); }
__device__ __forceinline__ bf16  f2b(float v){ return __float2bfloat16(v); }
__device__ __forceinline__ unsigned short f2bu(float x){
  bf16 h = __float2bfloat16(x);
  unsigned short u; __builtin_memcpy(&u,&h,2); return u;
}
__device__ __forceinline__ float bu2f(unsigned short u){
  unsigned int x = ((unsigned int)u)<<16; float f; __builtin_memcpy(&f,&x,4); return f;
}

// tab[k][n]: cos/sin(2*pi*k*n/201), k=0..12, exact mod-201 reduction
__global__ void k_tab(float* __restrict__ tab){
  int t = blockIdx.x*blockDim.x+threadIdx.x;
  if(t>=13*NN) return;
  int k=t/NN, n=t-k*NN;
  int m=(k*n)%NN;
  float ang = (2.0f*PI_F/201.0f)*(float)m;
  tab[2*t]   = cosf(ang);
  tab[2*t+1] = sinf(ang);
}

// Pack inverse-W twiddles into MFMA A-fragment order (bf16).
__global__ void k_tpack(const float* __restrict__ tab, unsigned short* __restrict__ TPK){
  int e = blockIdx.x*256 + threadIdx.x;
  if(e>=6656) return;
  int wt=e>>9, lane=(e>>3)&63, j=e&7;
  int m_=lane&15, g=lane>>4;
  int w = wt*16+m_;
  int k24 = g*8+j;
  float v=0.f;
  if(k24<24 && w<201){
    float2 cs = ((const float2*)tab)[(k24>>1)*NN + w];
    v = (k24&1)? cs.y : cs.x;
  }
  TPK[e]=f2bu(v);
}

// Pack forward-W twiddles into MFMA A-fragment order (bf16), sign folded.
__global__ void k_tpack2(const float* __restrict__ tab, unsigned short* __restrict__ T2PK){
  int e = blockIdx.x*256 + threadIdx.x;
  if(e>=7168) return;
  int idx = e>>9;
  int mt = idx/7, chunk = idx - mt*7;
  int lane=(e>>3)&63, j=e&7;
  int m_=lane&15, g=lane>>4;
  int kx24 = mt*16 + m_;
  int w = chunk*32 + g*8 + j;
  float v=0.f;
  if(kx24<24 && w<NN){
    float2 cs = ((const float2*)tab)[(kx24>>1)*NN + w];
    v = (kx24&1)? -cs.y : cs.x;
  }
  T2PK[e]=f2bu(v);
}

// Pack H-DFT twiddles: M=48 rows (j24*2+comp), K=402 (re:k<201, im:k>=201).
__global__ void k_tpack3(const float* __restrict__ tab, unsigned short* __restrict__ T3PK){
  int e = blockIdx.x*256 + threadIdx.x;
  if(e>=19968) return;
  int idx=e>>9;
  int mt=idx/13, chunk=idx-mt*13;
  int lane=(e>>3)&63, j=e&7;
  int m_=lane&15, g=lane>>4;
  int m = mt*16+m_;
  int k = chunk*32+g*8+j;
  float v=0.f;
  if(m<48 && k<402){
    int j24=m>>1, comp=m&1;
    int k2=(j24<12)? j24 : 24-j24;
    float sgn=(j24<12)? -1.f : 1.f;
    int h=(k<201)? k : k-201;
    float2 cs=((const float2*)tab)[k2*NN+h];
    float cc=cs.x, ss=sgn*cs.y;
    if(k<201) v = comp? ss : cc;
    else      v = comp? cc : -ss;
  }
  T3PK[e]=f2bu(v);
}

// Separable encoder tables. grid (192,2), 64 thr.
__global__ void k_pretab(const float* __restrict__ Wp, const float* __restrict__ bp,
                         float* __restrict__ Ux, float* __restrict__ Uy){
  int i = blockIdx.x;
  int ax = blockIdx.y;
  int c = threadIdx.x;
  float g = (float)i*(1.0f/191.0f);
  float acc;
  if(ax==0) acc = bp[c] + g*Wp[64+c];
  else      acc = g*Wp[128+c];
  int cosBase = (ax==0)? 3 : 4;
  int sinBase = (ax==0)? 23 : 24;
  #pragma unroll
  for(int l=0;l<10;l++){
    float f = PI_F*(float)(1<<l);
    float sv,cv;
    sincosf(g*f,&sv,&cv);
    acc += cv*Wp[(cosBase+2*l)*64+c] + sv*Wp[(sinBase+2*l)*64+c];
  }
  float* U = (ax==0)? Ux : Uy;
  U[i*64+c] = acc;
}

// Pack 16 64x64 weight matrices into bf16 MFMA-fragment order.
__global__ void k_wpack(const float* __restrict__ m1w, const float* __restrict__ m2w,
                        const float* __restrict__ ww,  const float* __restrict__ q1w,
                        unsigned short* __restrict__ WPK){
  int bx = blockIdx.x, tid = threadIdx.x;
  const float* src;
  if(bx<12){
    int l=bx/3, sel=bx-l*3;
    src = (sel==0)? m1w+(size_t)l*4096 : (sel==1)? m2w+(size_t)l*4096 : ww+(size_t)l*4096;
  } else {
    src = q1w + (size_t)(bx-12)*4096;
  }
  unsigned short* dst = WPK + (size_t)bx*4096;
  #pragma unroll
  for(int t=0;t<16;t++){
    int d = tid*16+t;
    int frag=d>>9, lane=(d>>3)&63, j=d&7;
    int mt=frag>>1, kh=frag&1, m_=lane&15, g=lane>>4;
    dst[d] = f2bu(src[(size_t)(16*mt+m_)*64 + 32*kh + 8*g + j]);
  }
}

// Transpose spectral weights for layer into bf16 WT[m][comp][io].
__global__ void __launch_bounds__(256) k_wtrans(const float* __restrict__ w1,
        const float* __restrict__ w2, unsigned short* __restrict__ WT){
  __shared__ float tile[64][65];
  int io0 = blockIdx.x*64;
  int c0  = blockIdx.y*64;
  int z   = blockIdx.z;
  const float* src = (z==0)? w1 : w2;
  int tid = threadIdx.x;
  #pragma unroll
  for(int it=0;it<16;it++){
    int e = tid + 256*it;
    int r = e>>6, c = e&63;
    if(c0+c<288) tile[r][c] = src[(size_t)(io0+r)*288 + c0 + c];
  }
  __syncthreads();
  #pragma unroll
  for(int it=0;it<16;it++){
    int e = tid + 256*it;
    int rp = e>>6, cp = e&63;
    int col = c0 + rp;
    if(col<288){
      int ky = col/24, rm = col - ky*24;
      int kx = rm>>1, comp = rm&1;
      int m = z*144 + ky*12 + kx;
      WT[(size_t)m*8192 + comp*4096 + io0 + cp] = f2bu(tile[cp][rp]);
    }
  }
}

// encoder: A[b][p][c] = x*Wp0[c] + Ux[hh][c] + Uy[ww][c]; zeros in pad.
__global__ void k_encoder(const float* __restrict__ x, const float* __restrict__ Wp,
                          const float* __restrict__ Ux, const float* __restrict__ Uy,
                          bf16* __restrict__ A){
  int tid=threadIdx.x;
  int p = blockIdx.x*256+tid;
  if(p>=NPIX) return;
  int b = blockIdx.y;
  uint4* dst = (uint4*)(A + ((size_t)b*NPIX + p)*64);
  int hh=p/NN, ww=p-hh*NN;
  if(hh>=SS || ww>=SS){
    uint4 z = {0,0,0,0};
    #pragma unroll
    for(int i=0;i<8;i++) dst[i]=z;
    return;
  }
  float xv = x[((size_t)b*SS+hh)*SS+ww];
  const float4* ux = (const float4*)(Ux + hh*64);
  const float4* uy = (const float4*)(Uy + ww*64);
  const float4* w0 = (const float4*)Wp;
  #pragma unroll
  for(int i=0;i<8;i++){
    float4 a0 = ux[2*i],   a1 = ux[2*i+1];
    float4 b0 = uy[2*i],   b1 = uy[2*i+1];
    float4 c0 = w0[2*i],   c1 = w0[2*i+1];
    float v0=xv*c0.x+a0.x+b0.x, v1=xv*c0.y+a0.y+b0.y;
    float v2=xv*c0.z+a0.z+b0.z, v3=xv*c0.w+a0.w+b0.w;
    float v4=xv*c1.x+a1.x+b1.x, v5=xv*c1.y+a1.y+b1.y;
    float v6=xv*c1.z+a1.z+b1.z, v7=xv*c1.w+a1.w+b1.w;
    uint4 v;
    v.x = (unsigned)f2bu(v0) | ((unsigned)f2bu(v1)<<16);
    v.y = (unsigned)f2bu(v2) | ((unsigned)f2bu(v3)<<16);
    v.z = (unsigned)f2bu(v4) | ((unsigned)f2bu(v5)<<16);
    v.w = (unsigned)f2bu(v6) | ((unsigned)f2bu(v7)<<16);
    dst[i]=v;
  }
}

// MFMA forward DFT along W. grid 402 x 4 waves; wave = one row R=b*201+h.
__global__ void __launch_bounds__(256) k_dftw(const bf16* __restrict__ A,
        const unsigned short* __restrict__ T2PK, bf16* __restrict__ XWb){
  int tid=threadIdx.x, wid=tid>>6, l=tid&63;
  int m_=l&15, g=l>>4;
  int R = blockIdx.x*4 + wid;
  const bf16* row = A + (size_t)R*NN*64;
  f32x4 acc[2][4];
  #pragma unroll
  for(int mt=0;mt<2;mt++){
    #pragma unroll
    for(int nt=0;nt<4;nt++) acc[mt][nt]=f32x4{0.f,0.f,0.f,0.f};
  }
  for(int chunk=0;chunk<7;chunk++){
    int wbase = chunk*32 + g*8;
    s8v bf[4];
    if(chunk<6){
      #pragma unroll
      for(int nt=0;nt<4;nt++){
        s8v f;
        #pragma unroll
        for(int j=0;j<8;j++){
          unsigned short v;
          bf16 hv = row[(size_t)(wbase+j)*64 + 16*nt + m_];
          __builtin_memcpy(&v,&hv,2);
          f[j]=(short)v;
        }
        bf[nt]=f;
      }
    } else {
      #pragma unroll
      for(int nt=0;nt<4;nt++){
        s8v f;
        #pragma unroll
        for(int j=0;j<8;j++){
          unsigned short v=0;
          if(wbase+j<NN){
            bf16 hv = row[(size_t)(wbase+j)*64 + 16*nt + m_];
            __builtin_memcpy(&v,&hv,2);
          }
          f[j]=(short)v;
        }
        bf[nt]=f;
      }
    }
    #pragma unroll
    for(int mt=0;mt<2;mt++){
      s8v af = *(const s8v*)(T2PK + (size_t)(mt*7+chunk)*512 + l*8);
      #pragma unroll
      for(int nt=0;nt<4;nt++)
        acc[mt][nt]=__builtin_amdgcn_mfma_f32_16x16x32_bf16(af,bf[nt],acc[mt][nt],0,0,0);
    }
  }
  int bb = R/NN, h = R - bb*NN;
  #pragma unroll
  for(int mt=0;mt<2;mt++){
    #pragma unroll
    for(int nt=0;nt<4;nt++){
      #pragma unroll
      for(int e=0;e<4;e++){
        int kx24 = mt*16 + 4*g + e;
        if(kx24<24){
          int plane = kx24&1, kx = kx24>>1;
          XWb[(size_t)plane*XWPL + (((size_t)bb*12+kx)*201 + h)*64 + 16*nt + m_]
            = f2b(acc[mt][nt][e]);
        }
      }
    }
  }
}

// MFMA H-DFT: grid (12, BB, 2); 4 waves, wave wid<3 owns m-tile wid; z = nt-half.
__global__ void __launch_bounds__(256) k_dfthM(const bf16* __restrict__ XWb,
        const unsigned short* __restrict__ T3PK, float* __restrict__ XF){
  int kx=blockIdx.x, b=blockIdx.y, zh=blockIdx.z;
  int tid=threadIdx.x, wid=tid>>6, l=tid&63;
  int m_=l&15, g=l>>4;
  if(wid>=3) return;
  const bf16* base = XWb + (((size_t)b*12+kx)*201)*64;
  f32x4 acc0=f32x4{0.f,0.f,0.f,0.f}, acc1=f32x4{0.f,0.f,0.f,0.f};
  for(int chunk=0;chunk<13;chunk++){
    s8v bf0, bf1;
    #pragma unroll
    for(int nt2=0;nt2<2;nt2++){
      int c = 16*(zh*2+nt2) + m_;
      s8v f;
      #pragma unroll
      for(int j=0;j<8;j++){
        int k = chunk*32 + g*8 + j;
        unsigned short v=0;
        if(k<402){
          int h = (k<201)? k : (k-201);
          size_t poff = (k<201)? 0 : (size_t)XWPL;
          bf16 hv = base[poff + (size_t)h*64 + c];
          __builtin_memcpy(&v,&hv,2);
        }
        f[j]=(short)v;
      }
      if(nt2==0) bf0=f; else bf1=f;
    }
    s8v af = *(const s8v*)(T3PK + (size_t)(wid*13+chunk)*512 + l*8);
    acc0=__builtin_amdgcn_mfma_f32_16x16x32_bf16(af,bf0,acc0,0,0,0);
    acc1=__builtin_amdgcn_mfma_f32_16x16x32_bf16(af,bf1,acc1,0,0,0);
  }
  #pragma unroll
  for(int nt2=0;nt2<2;nt2++){
    f32x4 a = (nt2==0)? acc0 : acc1;
    int c = 16*(zh*2+nt2) + m_;
    #pragma unroll
    for(int e2=0;e2<4;e2++){
      int m = wid*16 + 4*g + e2;
      int j24 = m>>1, comp = m&1;
      XF[(size_t)(j24*12+kx)*1024 + ((size_t)b*64+c)*2 + comp] = a[e2];
    }
  }
}

// per-mode 64x64 complex mix; bf16 weights staged to fp32 LDS; ILP split accs.
__global__ void __launch_bounds__(512) k_modemix(const float* __restrict__ XF,
     const unsigned short* __restrict__ WT, float* __restrict__ XO){
  __shared__ float sx[1024];
  __shared__ float swr[4096], swi[4096];
  int m=blockIdx.x;
  int tid=threadIdx.x;
  sx[tid]     = XF[(size_t)m*1024+tid];
  sx[tid+512] = XF[(size_t)m*1024+tid+512];
  const unsigned short* wr = WT + (size_t)m*8192;
  const unsigned short* wi = wr + 4096;
  for(int io=tid;io<4096;io+=512){
    swr[io]=bu2f(wr[io]);
    swi[io]=bu2f(wi[io]);
  }
  __syncthreads();
  int b=tid>>6, o=tid&63;
  const float* xb = sx + b*128;
  float re0=0.f,re1=0.f,im0=0.f,im1=0.f;
  #pragma unroll 8
  for(int i=0;i<64;i+=2){
    float a=xb[2*i], b2=xb[2*i+1];
    float c=swr[i*64+o], d=swi[i*64+o];
    re0 = fmaf(a,c, fmaf(-b2,d, re0));
    im0 = fmaf(a,d, fmaf( b2,c, im0));
    float a1=xb[2*i+2], b3=xb[2*i+3];
    float c1=swr[(i+1)*64+o], d1=swi[(i+1)*64+o];
    re1 = fmaf(a1,c1, fmaf(-b3,d1, re1));
    im1 = fmaf(a1,d1, fmaf( b3,c1, im1));
  }
  XO[2*((size_t)m*512+tid)]  =re0+re1;
  XO[2*((size_t)m*512+tid)+1]=im0+im1;
}

// Merged inverse: per row R, idfth into LDS (factors folded), then the C2R
// along W as MFMA: C[w][o] = sum_k24 T[w][k24]*Y24[k24][o], T prepacked (TPK).
__global__ void __launch_bounds__(256) k_ispec(const float* __restrict__ XO,
        const float* __restrict__ tab, const unsigned short* __restrict__ TPK,
        bf16* __restrict__ C){
  __shared__ float2 yl[12][64];
  __shared__ float2 cs13[13];
  int R=blockIdx.x;
  int b=R/NN, h=R-b*NN;
  int tid=threadIdx.x;
  if(tid<13) cs13[tid]=((const float2*)tab)[tid*NN+h];
  __syncthreads();
  const float sc = 1.0f/40401.0f;
  #pragma unroll
  for(int it=0;it<3;it++){
    int item = tid + 256*it;
    int kx = item>>6, o = item&63;
    float re0=0.f,im0=0.f,re1=0.f,im1=0.f;
    #pragma unroll
    for(int j=0;j<24;j+=2){
      {
        int k2=(j<12)?j:24-j;
        float sgn=(j<12)?1.0f:-1.0f;
        float2 xo = *(const float2*)(XO + 2*(((size_t)(j*12+kx)*512) + b*64 + o));
        float2 cs = cs13[k2];
        float cc=cs.x, s2=sgn*cs.y;
        re0 = fmaf(xo.x,cc, fmaf(-xo.y,s2, re0));
        im0 = fmaf(xo.x,s2, fmaf( xo.y,cc, im0));
      }
      {
        int j1=j+1;
        int k2=(j1<12)?j1:24-j1;
        float sgn=(j1<12)?1.0f:-1.0f;
        float2 xo = *(const float2*)(XO + 2*(((size_t)(j1*12+kx)*512) + b*64 + o));
        float2 cs = cs13[k2];
        float cc=cs.x, s2=sgn*cs.y;
        re1 = fmaf(xo.x,cc, fmaf(-xo.y,s2, re1));
        im1 = fmaf(xo.x,s2, fmaf( xo.y,cc, im1));
      }
    }
    float fr = (kx==0)? sc : 2.0f*sc;
    float fi = (kx==0)? sc : -2.0f*sc;
    yl[kx][o] = float2{ (re0+re1)*fr, (im0+im1)*fi };
  }
  __syncthreads();
  int wid=tid>>6, l=tid&63, m_=l&15, g=l>>4;
  int o = wid*16 + m_;
  s8v bfr;
  #pragma unroll
  for(int j=0;j<4;j++){
    float2 v = yl[4*g+j][o];
    bfr[2*j]   = (short)f2bu(v.x);
    bfr[2*j+1] = (short)f2bu(v.y);
  }
  bf16* cp = C + (size_t)R*NN*64;
  #pragma unroll
  for(int wt=0; wt<13; wt++){
    s8v af = *(const s8v*)(TPK + (size_t)wt*512 + l*8);
    f32x4 acc = f32x4{0.f,0.f,0.f,0.f};
    acc = __builtin_amdgcn_mfma_f32_16x16x32_bf16(af, bfr, acc, 0,0,0);
    #pragma unroll
    for(int e=0;e<4;e++){
      int w = wt*16 + 4*g + e;
      if(w<NN) cp[(size_t)w*64 + o] = f2b(acc[e]);
    }
  }
}

// Chunked Parseval Gram from XO: grid (9, BB). Block = 64-feature chunk.
__global__ void __launch_bounds__(256) k_gramC(const float* __restrict__ XO,
        float* __restrict__ GCp, float* __restrict__ SC){
  __shared__ unsigned short V[64][72];
  int chunk=blockIdx.x, b=blockIdx.y, tid=threadIdx.x;
  const float s1=1.0f/201.0f;
  const float r2=0.70710678118f;
  const float q2=1.41421356237f;
  #pragma unroll
  for(int it=0;it<16;it++){
    int e = tid + it*256;
    int fl=e>>6, ch=e&63;
    int f = chunk*64 + fl;
    int base = b*64+ch;
    float v=0.f;
    if(f<528){
      int comp=f&1, kxm=f>>1;
      int kx0=kxm/24;
      int kx=1+kx0, m=kxm-kx0*24;
      v = q2*XO[2*((size_t)(m*12+kx)*512 + base)+comp];
    } else if(f==528){
      v = XO[2*(size_t)base];
    } else if(f<551){
      int q=f-529; int mm=1+(q>>1);
      const float* p1 = XO + 2*((size_t)(mm*12)*512 + base);
      const float* p2 = XO + 2*((size_t)((24-mm)*12)*512 + base);
      v = ((q&1)==0)? r2*(p1[0]+p2[0]) : r2*(p1[1]-p2[1]);
    } else if(f==551){
      v = r2*XO[2*((size_t)(144)*512 + base)];
    } else if(f==552){
      v = r2*XO[2*((size_t)(144)*512 + base)+1];
    }
    V[ch][fl]=f2bu(v*s1);
  }
  __syncthreads();
  int wid=tid>>6, l=tid&63, m_=l&15, g=l>>4;
  f32x4 acc[4];
  #pragma unroll
  for(int mt=0;mt<4;mt++) acc[mt]=f32x4{0.f,0.f,0.f,0.f};
  #pragma unroll
  for(int kc=0;kc<2;kc++){
    s8v bfr = *(const s8v*)&V[16*wid+m_][kc*32+8*g];
    #pragma unroll
    for(int mt=0;mt<4;mt++){
      s8v afr = *(const s8v*)&V[16*mt+m_][kc*32+8*g];
      acc[mt]=__builtin_amdgcn_mfma_f32_16x16x32_bf16(afr,bfr,acc[mt],0,0,0);
    }
  }
  float* gb = GCp + ((size_t)(b*9+chunk))*4096;
  #pragma unroll
  for(int mt=0;mt<4;mt++){
    #pragma unroll
    for(int e=0;e<4;e++)
      gb[(size_t)(16*mt+4*g+e)*64 + 16*wid + m_] = acc[mt][e];
  }
  if(chunk==0 && tid<64) SC[b*64+tid] = XO[2*(size_t)(b*64+tid)];
}

// MFMA Gram v2: fragments loaded directly from global. grid (nblkx, BB) x 4 waves.
__global__ void __launch_bounds__(256) k_gramp(const bf16* __restrict__ X,
        float* __restrict__ Gpart, float* __restrict__ Spart, int HR, int WR){
  int b = blockIdx.y, blk = blockIdx.x;
  int npix = HR*WR;
  int tid=threadIdx.x, wid=tid>>6, l=tid&63;
  int m_=l&15, g=l>>4;
  int slab = blk*4 + wid;
  const bf16* xb = X + (size_t)b*NPIX*64;
  f32x4 acc[4][4];
  #pragma unroll
  for(int mt=0;mt<4;mt++){
    #pragma unroll
    for(int nt=0;nt<4;nt++) acc[mt][nt]=f32x4{0.f,0.f,0.f,0.f};
  }
  float cs[4]={0.f,0.f,0.f,0.f};
  for(int kc=0;kc<16;kc++){
    int pbase = slab*512 + kc*32 + g*8;
    int hh0=0, ww0=0;
    if(WR!=NN){ hh0 = pbase/WR; ww0 = pbase - hh0*WR; }
    const bf16* ptr[8];
    #pragma unroll
    for(int jj=0;jj<8;jj++){
      int p = pbase + jj;
      int gp;
      if(WR==NN) gp = p;
      else {
        int ww2 = ww0 + jj;
        int hh  = hh0;
        if(ww2>=WR){ ww2-=WR; hh++; }
        gp = hh*NN + ww2;
      }
      ptr[jj] = (p<npix) ? (xb + (size_t)gp*64) : (const bf16*)0;
    }
    s8v fr[4];
    #pragma unroll
    for(int t=0;t<4;t++){
      s8v f;
      float s=0.f;
      #pragma unroll
      for(int jj=0;jj<8;jj++){
        unsigned short v=0;
        if(ptr[jj]){ bf16 hv = ptr[jj][16*t+m_]; __builtin_memcpy(&v,&hv,2); }
        f[jj]=(short)v;
        s += bu2f(v);
      }
      fr[t]=f;
      cs[t]+=s;
    }
    #pragma unroll
    for(int nt=0;nt<4;nt++){
      #pragma unroll
      for(int mt=0;mt<4;mt++)
        acc[mt][nt]=__builtin_amdgcn_mfma_f32_16x16x32_bf16(fr[mt],fr[nt],acc[mt][nt],0,0,0);
    }
  }
  float* gp_ = Gpart + ((size_t)(b*GNB + slab))*4096;
  #pragma unroll
  for(int mt=0;mt<4;mt++){
    #pragma unroll
    for(int nt=0;nt<4;nt++){
      #pragma unroll
      for(int e=0;e<4;e++)
        gp_[(size_t)(16*mt + 4*g + e)*64 + 16*nt + m_] = acc[mt][nt][e];
    }
  }
  #pragma unroll
  for(int t=0;t<4;t++){
    float s=cs[t];
    s += __shfl_xor(s,16,64);
    s += __shfl_xor(s,32,64);
    if(g==0) Spart[((size_t)(b*GNB+slab))*64 + 16*t + m_] = s;
  }
}

// Parallel slab reduce: grid (16, BB). Gfin[b][4096], Sfin[b][64].
__global__ void __launch_bounds__(256) k_gramr(const float* __restrict__ Gpart,
        const float* __restrict__ Spart, float* __restrict__ Gfin,
        float* __restrict__ Sfin, int nblk){
  int b = blockIdx.y;
  int idx = blockIdx.x*256 + threadIdx.x;
  float s0=0.f,s1=0.f,s2=0.f,s3=0.f;
  int k=0;
  for(;k+3<nblk;k+=4){
    s0 += Gpart[((size_t)b*GNB + k  )*4096 + idx];
    s1 += Gpart[((size_t)b*GNB + k+1)*4096 + idx];
    s2 += Gpart[((size_t)b*GNB + k+2)*4096 + idx];
    s3 += Gpart[((size_t)b*GNB + k+3)*4096 + idx];
  }
  for(;k<nblk;k++) s0 += Gpart[((size_t)b*GNB + k)*4096 + idx];
  Gfin[(size_t)b*4096 + idx] = (s0+s1)+(s2+s3);
  if(blockIdx.x==0 && threadIdx.x<64){
    float ss=0.f;
    for(int j=0;j<nblk;j++) ss += Spart[((size_t)b*GNB + j)*64 + threadIdx.x];
    Sfin[b*64 + threadIdx.x]=ss;
  }
}

// Stats for layer (grid 32): zb2 = zb*2+grp. zb<8 -> Cb (chunked GCp + SC);
// zb>=8 -> A (Gfin/Sfin). Block = one GN group of 32 rows; i split 8-ways.
__global__ void __launch_bounds__(256) k_statsA(
        const float* __restrict__ GCp, const float* __restrict__ SC,
        const float* __restrict__ Gfin, const float* __restrict__ Sfin,
        const float* __restrict__ m1wl, const float* __restrict__ m1bl,
        const float* __restrict__ wwl,  const float* __restrict__ wbl,
        float* __restrict__ TSTAT, float* __restrict__ USTAT){
  __shared__ float Gs[4096];
  __shared__ float Ss[64];
  __shared__ float rs[256], rq[256];
  int zb2=blockIdx.x;
  int zb=zb2>>1, grp=zb2&1;
  int t=threadIdx.x;
  if(zb<8){
    #pragma unroll
    for(int e=0;e<16;e++){
      float s=0.f;
      #pragma unroll
      for(int q=0;q<9;q++) s += GCp[((size_t)(zb*9+q))*4096 + t*16+e];
      Gs[t*16+e]=s;
    }
    if(t<64) Ss[t]=SC[zb*64+t];
  } else {
    const float* GS = Gfin + (size_t)(zb-8)*4096;
    #pragma unroll
    for(int e=0;e<16;e++) Gs[t*16+e]=GS[t*16+e];
    if(t<64) Ss[t]=Sfin[(zb-8)*64+t];
  }
  __syncthreads();
  const float* W    = (zb<8)? m1wl : wwl;
  const float* bias = (zb<8)? m1bl : wbl;
  float* stat       = (zb<8)? TSTAT : USTAT;
  int b = (zb<8)? zb : zb-8;
  int o = grp*32 + (t&31);
  int sl = t>>5;
  float w[64];
  #pragma unroll
  for(int j2=0;j2<64;j2++) w[j2]=bu2f(f2bu(W[(size_t)o*64+j2]));
  const float* Gr = Gs + (size_t)(sl*8)*64;
  float quad=0.f;
  #pragma unroll
  for(int r=0;r<8;r++){
    const float* gr = Gr + r*64;
    float tt=0.f;
    #pragma unroll
    for(int j2=0;j2<64;j2++) tt += gr[j2]*w[j2];
    quad += w[sl*8+r]*tt;
  }
  float sm=0.f, sq=quad;
  if(sl==0){
    float dot=0.f;
    #pragma unroll
    for(int j2=0;j2<64;j2++) dot += w[j2]*Ss[j2];
    float bo = bias[o];
    float Nf = (float)NPIX;
    sm = dot + Nf*bo;
    sq += 2.f*bo*dot + Nf*bo*bo;
  }
  rs[t]=sm; rq[t]=sq;
  __syncthreads();
  if(t<32){
    float s2=0.f,q2=0.f;
    #pragma unroll
    for(int k=0;k<8;k++){ s2+=rs[t+32*k]; q2+=rq[t+32*k]; }
    for(int off=16;off>0;off>>=1){
      s2 += __shfl_down(s2,off,32);
      q2 += __shfl_down(q2,off,32);
    }
    if(t==0){
      float invN = 1.f/((float)NPIX*32.f);
      float mean = s2*invN;
      float var = q2*invN - mean*mean;
      stat[b*4+grp*2]   = mean;
      stat[b*4+grp*2+1] = rsqrtf(fmaxf(var,0.f)+1e-5f);
    }
  }
}

// Head stats partials: grid (BB, 4). Block = 64 rows; i split 4-ways.
__global__ void __launch_bounds__(256) k_statsQ(const float* __restrict__ Gfin,
        const float* __restrict__ Sfin,
        const float* __restrict__ W, const float* __restrict__ bias,
        float* __restrict__ QP){
  __shared__ float Gs[4096];
  __shared__ float Ss[64];
  __shared__ float rs[256], rq[256];
  int b=blockIdx.x, z=blockIdx.y, t=threadIdx.x;
  #pragma unroll
  for(int e=0;e<16;e++) Gs[t*16+e]=Gfin[(size_t)b*4096 + t*16+e];
  if(t<64) Ss[t]=Sfin[b*64+t];
  __syncthreads();
  int o = z*64 + (t&63);
  int sl = t>>6;
  float w[64];
  #pragma unroll
  for(int j2=0;j2<64;j2++) w[j2]=bu2f(f2bu(W[(size_t)o*64+j2]));
  const float* Gr = Gs + (size_t)(sl*16)*64;
  float quad=0.f;
  #pragma unroll
  for(int r=0;r<16;r++){
    const float* gr = Gr + r*64;
    float tt=0.f;
    #pragma unroll
    for(int j2=0;j2<64;j2++) tt += gr[j2]*w[j2];
    quad += w[sl*16+r]*tt;
  }
  float sm=0.f, sq=quad;
  if(sl==0){
    float dot=0.f;
    #pragma unroll
    for(int j2=0;j2<64;j2++) dot += w[j2]*Ss[j2];
    float bo=bias[o];
    float Nf=(float)QPIX;
    sm = dot + Nf*bo;
    sq += 2.f*bo*dot + Nf*bo*bo;
  }
  rs[t]=sm; rq[t]=sq;
  __syncthreads();
  if(t<64){
    float s2 = rs[t]+rs[t+64]+rs[t+128]+rs[t+192];
    float q2 = rq[t]+rq[t+64]+rq[t+128]+rq[t+192];
    for(int off=32;off>0;off>>=1){
      s2 += __shfl_down(s2,off,64);
      q2 += __shfl_down(q2,off,64);
    }
    if(t==0){
      int g = z>>1;
      atomicAdd(&QP[b*4+g*2],   s2);
      atomicAdd(&QP[b*4+g*2+1], q2);
    }
  }
}

// Finalize head stats. grid 1, 16 threads.
__global__ void k_qfin(const float* __restrict__ QP, float* __restrict__ QSTAT){
  int t=threadIdx.x;
  if(t>=16) return;
  int b=t>>1, g=t&1;
  float s=QP[b*4+g*2], ss=QP[b*4+g*2+1];
  float invN=1.f/((float)QPIX*128.f);
  float mean=s*invN, var=ss*invN-mean*mean;
  QSTAT[b*4+g*2]   = mean;
  QSTAT[b*4+g*2+1] = rsqrtf(fmaxf(var,0.f)+1e-5f);
}

// MFMA fused layer, 2-wave 128px blocks; vlds is wave-private -> NO barrier.
__global__ void __launch_bounds__(128) k_fuse(const bf16* __restrict__ Cb,
    bf16* __restrict__ A,
    const unsigned short* __restrict__ wp1, const float* __restrict__ m1b,
    const float* __restrict__ mg,  const float* __restrict__ mbt,
    const unsigned short* __restrict__ wp2, const float* __restrict__ m2b,
    const unsigned short* __restrict__ wpw, const float* __restrict__ wbk,
    const float* __restrict__ ng,  const float* __restrict__ nb,
    const float* __restrict__ tstat, const float* __restrict__ ustat, int last){
  __shared__ unsigned short vlds[2][64][72];
  int tid=threadIdx.x;
  int wid=tid>>6, l=tid&63;
  int m_=l&15, g=l>>4;
  int b=blockIdx.y;
  int p0=blockIdx.x*128 + wid*64;
  const bf16* cbb = Cb + (size_t)b*NPIX*64;
  const bf16* ab  = A  + (size_t)b*NPIX*64;

  s8v af[4][2];
  f32x4 acc[4][4];

  // ---- GEMM1: t = m1w @ Cb + m1b ----
  #pragma unroll
  for(int mt=0;mt<4;mt++){
    #pragma unroll
    for(int kh=0;kh<2;kh++)
      af[mt][kh]=*(const s8v*)(wp1 + (mt*2+kh)*512 + l*8);
    float4 b4 = *(const float4*)(m1b + 16*mt + 4*g);
    #pragma unroll
    for(int nt=0;nt<4;nt++) acc[mt][nt]=f32x4{b4.x,b4.y,b4.z,b4.w};
  }
  #pragma unroll
  for(int nt=0;nt<4;nt++){
    int p = p0 + 16*nt + m_;
    int pc = p<NPIX? p : NPIX-1;
    const s8v* xb = (const s8v*)(cbb + (size_t)pc*64);
    s8v b0 = xb[g], b1 = xb[4+g];
    #pragma unroll
    for(int mt=0;mt<4;mt++){
      acc[mt][nt]=__builtin_amdgcn_mfma_f32_16x16x32_bf16(af[mt][0],b0,acc[mt][nt],0,0,0);
      acc[mt][nt]=__builtin_amdgcn_mfma_f32_16x16x32_bf16(af[mt][1],b1,acc[mt][nt],0,0,0);
    }
  }
  // ---- epilogue1: GN+gelu -> vlds (wave-private) ----
  {
    float tm0=tstat[b*4],tr0=tstat[b*4+1],tm1=tstat[b*4+2],tr1=tstat[b*4+3];
    #pragma unroll
    for(int mt=0;mt<4;mt++){
      float4 g4 = *(const float4*)(mg  + 16*mt + 4*g);
      float4 t4 = *(const float4*)(mbt + 16*mt + 4*g);
      float mn = (mt<2)? tm0 : tm1;
      float rs = (mt<2)? tr0 : tr1;
      float ax=rs*g4.x, ay=rs*g4.y, az=rs*g4.z, aw=rs*g4.w;
      float cx=t4.x-mn*ax, cy=t4.y-mn*ay, cz=t4.z-mn*az, cw=t4.w-mn*aw;
      #pragma unroll
      for(int nt=0;nt<4;nt++){
        int pl = 16*nt + m_;
        f32x4 t = acc[mt][nt];
        float v0 = gelu_f(fmaf(t[0],ax,cx));
        float v1 = gelu_f(fmaf(t[1],ay,cy));
        float v2 = gelu_f(fmaf(t[2],az,cz));
        float v3 = gelu_f(fmaf(t[3],aw,cw));
        uint2 pk;
        pk.x = (unsigned)f2bu(v0) | ((unsigned)f2bu(v1)<<16);
        pk.y = (unsigned)f2bu(v2) | ((unsigned)f2bu(v3)<<16);
        *(uint2*)&vlds[wid][pl][16*mt+4*g] = pk;
      }
    }
  }
  // ---- GEMM3: u = ww @ A + wb (no barrier; vlds writes drain under these loads) ----
  #pragma unroll
  for(int mt=0;mt<4;mt++){
    #pragma unroll
    for(int kh=0;kh<2;kh++)
      af[mt][kh]=*(const s8v*)(wpw + (mt*2+kh)*512 + l*8);
    float4 b4 = *(const float4*)(wbk + 16*mt + 4*g);
    #pragma unroll
    for(int nt=0;nt<4;nt++) acc[mt][nt]=f32x4{b4.x,b4.y,b4.z,b4.w};
  }
  #pragma unroll
  for(int nt=0;nt<4;nt++){
    int p = p0 + 16*nt + m_;
    int pc = p<NPIX? p : NPIX-1;
    const s8v* xb = (const s8v*)(ab + (size_t)pc*64);
    s8v b0 = xb[g], b1 = xb[4+g];
    #pragma unroll
    for(int mt=0;mt<4;mt++){
      acc[mt][nt]=__builtin_amdgcn_mfma_f32_16x16x32_bf16(af[mt][0],b0,acc[mt][nt],0,0,0);
      acc[mt][nt]=__builtin_amdgcn_mfma_f32_16x16x32_bf16(af[mt][1],b1,acc[mt][nt],0,0,0);
    }
  }
  // ---- epilogue3: acc = m2b + GN(u) ----
  {
    float um0=ustat[b*4],ur0=ustat[b*4+1],um1=ustat[b*4+2],ur1=ustat[b*4+3];
    #pragma unroll
    for(int mt=0;mt<4;mt++){
      float4 n4 = *(const float4*)(ng  + 16*mt + 4*g);
      float4 nb4= *(const float4*)(nb  + 16*mt + 4*g);
      float4 m24= *(const float4*)(m2b + 16*mt + 4*g);
      float mn = (mt<2)? um0 : um1;
      float rs = (mt<2)? ur0 : ur1;
      float ax=rs*n4.x, ay=rs*n4.y, az=rs*n4.z, aw=rs*n4.w;
      float cx=m24.x+nb4.x-mn*ax, cy=m24.y+nb4.y-mn*ay;
      float cz=m24.z+nb4.z-mn*az, cw=m24.w+nb4.w-mn*aw;
      #pragma unroll
      for(int nt=0;nt<4;nt++){
        f32x4 u = acc[mt][nt];
        u[0] = fmaf(u[0],ax,cx);
        u[1] = fmaf(u[1],ay,cy);
        u[2] = fmaf(u[2],az,cz);
        u[3] = fmaf(u[3],aw,cw);
        acc[mt][nt]=u;
      }
    }
  }
  // ---- GEMM2: acc += m2w @ v (reads own wave's vlds) ----
  #pragma unroll
  for(int mt=0;mt<4;mt++){
    #pragma unroll
    for(int kh=0;kh<2;kh++)
      af[mt][kh]=*(const s8v*)(wp2 + (mt*2+kh)*512 + l*8);
  }
  #pragma unroll
  for(int nt=0;nt<4;nt++){
    int pl = 16*nt + m_;
    const s8v* vp = (const s8v*)&vlds[wid][pl][0];
    s8v b0 = vp[g], b1 = vp[4+g];
    #pragma unroll
    for(int mt=0;mt<4;mt++){
      acc[mt][nt]=__builtin_amdgcn_mfma_f32_16x16x32_bf16(af[mt][0],b0,acc[mt][nt],0,0,0);
      acc[mt][nt]=__builtin_amdgcn_mfma_f32_16x16x32_bf16(af[mt][1],b1,acc[mt][nt],0,0,0);
    }
  }
  // ---- final: h = gelu?(x1+x2) -> A ----
  #pragma unroll
  for(int nt=0;nt<4;nt++){
    int p = p0 + 16*nt + m_;
    if(p>=NPIX) continue;
    bf16* dp = A + ((size_t)b*NPIX + p)*64;
    #pragma unroll
    for(int mt=0;mt<4;mt++){
      f32x4 h = acc[mt][nt];
      float h0=h[0],h1=h[1],h2=h[2],h3=h[3];
      if(!last){ h0=gelu_f(h0); h1=gelu_f(h1); h2=gelu_f(h2); h3=gelu_f(h3); }
      uint2 pk;
      pk.x = (unsigned)f2bu(h0) | ((unsigned)f2bu(h1)<<16);
      pk.y = (unsigned)f2bu(h2) | ((unsigned)f2bu(h3)<<16);
      *(uint2*)(dp + 16*mt + 4*g) = pk;
    }
  }
}

// Head: 128px/block (grid 288,BB); wave = one oc chunk over 8 nt; folded GN coeffs.
__global__ void __launch_bounds__(256) k_qout(const bf16* __restrict__ A,
    const unsigned short* __restrict__ qpack, const float* __restrict__ q1b,
    const float* __restrict__ qg, const float* __restrict__ qbt,
    const float* __restrict__ q2w, const float* __restrict__ q2b,
    const float* __restrict__ qstat, float* __restrict__ out){
  __shared__ unsigned short xq[128][72];
  __shared__ float part[4][128];
  int tid=threadIdx.x;
  int wid=tid>>6, l=tid&63;
  int m_=l&15, g=l>>4;
  int b=blockIdx.y;
  int px0=blockIdx.x*128;
  {
    int p = px0 + (tid>>1);
    int half = tid&1;
    int hh=p/SS, ww2=p-hh*SS;
    const uint4* src=(const uint4*)(A + (((size_t)b*NPIX) + (size_t)hh*NN + ww2)*64 + half*32);
    uint4* drow=(uint4*)&xq[tid>>1][half*32];
    #pragma unroll
    for(int i=0;i<4;i++) drow[i]=src[i];
  }
  __syncthreads();
  int oc=wid;
  const unsigned short* wp = qpack + (size_t)oc*4096;
  s8v af[4][2];
  f32x4 bi4[4];
  float4 a4[4], c4[4], w4[4];
  float m0=qstat[b*4],r0=qstat[b*4+1],m1=qstat[b*4+2],r1=qstat[b*4+3];
  float mn=(oc<2)?m0:m1, rs=(oc<2)?r0:r1;
  #pragma unroll
  for(int mt=0;mt<4;mt++){
    #pragma unroll
    for(int kh=0;kh<2;kh++)
      af[mt][kh]=*(const s8v*)(wp + (mt*2+kh)*512 + l*8);
    float4 b4=*(const float4*)(q1b + 64*oc + 16*mt + 4*g);
    bi4[mt]=f32x4{b4.x,b4.y,b4.z,b4.w};
    float4 g4=*(const float4*)(qg  + 64*oc + 16*mt + 4*g);
    float4 t4=*(const float4*)(qbt + 64*oc + 16*mt + 4*g);
    w4[mt]=*(const float4*)(q2w + 64*oc + 16*mt + 4*g);
    a4[mt]=float4{rs*g4.x, rs*g4.y, rs*g4.z, rs*g4.w};
    c4[mt]=float4{t4.x-mn*a4[mt].x, t4.y-mn*a4[mt].y, t4.z-mn*a4[mt].z, t4.w-mn*a4[mt].w};
  }
  #pragma unroll
  for(int nt=0;nt<8;nt++){
    const s8v* vp = (const s8v*)&xq[16*nt+m_][0];
    s8v b0=vp[g], b1=vp[4+g];
    f32x4 acc[4];
    #pragma unroll
    for(int mt=0;mt<4;mt++) acc[mt]=bi4[mt];
    #pragma unroll
    for(int mt=0;mt<4;mt++){
      acc[mt]=__builtin_amdgcn_mfma_f32_16x16x32_bf16(af[mt][0],b0,acc[mt],0,0,0);
      acc[mt]=__builtin_amdgcn_mfma_f32_16x16x32_bf16(af[mt][1],b1,acc[mt],0,0,0);
    }
    float pp=0.f;
    #pragma unroll
    for(int mt=0;mt<4;mt++){
      f32x4 t=acc[mt];
      pp += gelu_f(fmaf(t[0],a4[mt].x,c4[mt].x))*w4[mt].x;
      pp += gelu_f(fmaf(t[1],a4[mt].y,c4[mt].y))*w4[mt].y;
      pp += gelu_f(fmaf(t[2],a4[mt].z,c4[mt].z))*w4[mt].z;
      pp += gelu_f(fmaf(t[3],a4[mt].w,c4[mt].w))*w4[mt].w;
    }
    pp += __shfl_xor(pp,16,64);
    pp += __shfl_xor(pp,32,64);
    if(g==0) part[wid][16*nt+m_]=pp;
  }
  __syncthreads();
  if(tid<128)
    out[(size_t)b*QPIX + px0 + tid] =
        q2b[0] + part[0][tid]+part[1][tid]+part[2][tid]+part[3][tid];
}

extern "C" void kernel_launch(void* const* d_in, const int* in_sizes, int n_in,
                              void* d_out, int out_size, void* d_ws, size_t ws_size,
                              hipStream_t stream){
  const float* x   = (const float*)d_in[0];
  const float* Wp  = (const float*)d_in[1];
  const float* bp  = (const float*)d_in[2];
  const float* sw1 = (const float*)d_in[3];
  const float* sw2 = (const float*)d_in[4];
  const float* m1w = (const float*)d_in[5];
  const float* m1b = (const float*)d_in[6];
  const float* mg  = (const float*)d_in[7];
  const float* mbt = (const float*)d_in[8];
  const float* m2w = (const float*)d_in[9];
  const float* m2b = (const float*)d_in[10];
  const float* ww  = (const float*)d_in[11];
  const float* wb  = (const float*)d_in[12];
  const float* ng  = (const float*)d_in[13];
  const float* nb  = (const float*)d_in[14];
  const float* q1w = (const float*)d_in[15];
  const float* q1b = (const float*)d_in[16];
  const float* qg  = (const float*)d_in[17];
  const float* qbt = (const float*)d_in[18];
  const float* q2w = (const float*)d_in[19];
  const float* q2b = (const float*)d_in[20];
  float* out = (float*)d_out;

  char* w8 = (char*)d_ws;
  const size_t ACT_B = (size_t)64*BB*NPIX*sizeof(bf16);   // 41,370,624
  bf16*  A    = (bf16*)(w8);
  bf16*  Cb   = (bf16*)(w8 + ACT_B);
  float* SPEC = (float*)(w8 + 2*ACT_B);                    // XWb / Gpart overlays
  float* XF   = (float*)(w8 + 2*ACT_B + 9879552);
  float* XO   = (float*)(w8 + 2*ACT_B + 9879552 + 1179648);
  float* TB   = (float*)(w8 + 2*ACT_B + 9879552 + 2*1179648);
  char*  g8   = w8 + 2*ACT_B + 9879552 + 2*1179648 + 20992;
  float* TSTAT= (float*)g8;
  float* USTAT= TSTAT + 32;
  float* QSTAT= USTAT + 32;
  float* UxT  = QSTAT + 32;                  // 192*64
  float* UyT  = UxT + 12288;                 // 192*64
  unsigned short* WPK = (unsigned short*)(UyT + 12288);   // 16*4096 bf16
  float* GFIN = (float*)(WPK + 16*4096);     // 8*4096 (reduced bypass gram)
  float* SFIN = GFIN + 8*4096;               // 8*64
  float* SC   = SFIN + 8*64;                 // 8*64 (Parseval col sums)
  unsigned short* TPK = (unsigned short*)(SC + 8*64);     // 13*512 inverse twiddles
  unsigned short* T2PK = TPK + 6656;                      // 14*512 forward twiddles
  unsigned short* T3PK = T2PK + 7168;                     // 39*512 H-DFT twiddles
  float* QP   = (float*)(T3PK + 19968);      // 32 (head stat partials)
  float* GCp  = QP + 32;                     // 8*9*4096 (Parseval partials)
  unsigned short* WT = (unsigned short*)(GCp + (size_t)8*9*4096); // 288*8192 bf16
  bf16*  XWb  = (bf16*)SPEC;                 // 2*XWPL bf16 = 4.94MB (SPEC overlay)
  float* Gpart = SPEC;                       // 8*80*4096 fl = 10.49MB <= SPEC+XF
  float* Spart = Gpart + (size_t)8*GNB*4096;
  size_t needed = (size_t)(2*ACT_B) + 9879552 + 2*1179648 + 20992
                + 3*32*4 + 2*12288*4 + 16*4096*2 + (8*4096+2*8*64)*4
                + 13312 + 14336 + 39936 + 128
                + (size_t)8*9*4096*4 + (size_t)288*8192*2;
  if(ws_size < needed) return;

  k_tab<<<11,256,0,stream>>>(TB);
  k_tpack<<<26,256,0,stream>>>(TB, TPK);
  k_tpack2<<<28,256,0,stream>>>(TB, T2PK);
  k_tpack3<<<78,256,0,stream>>>(TB, T3PK);
  k_pretab<<<dim3(192,2),64,0,stream>>>(Wp, bp, UxT, UyT);
  k_wpack<<<16,256,0,stream>>>(m1w, m2w, ww, q1w, WPK);
  k_encoder<<<dim3(158,BB),256,0,stream>>>(x, Wp, UxT, UyT, A);

  for(int l=0;l<4;l++){
    const float* sw1l = sw1 + (size_t)l*1179648;
    const float* sw2l = sw2 + (size_t)l*1179648;
    k_dftw<<<402,256,0,stream>>>(A, T2PK, XWb);
    k_dfthM<<<dim3(12,BB,2),256,0,stream>>>(XWb, T3PK, XF);
    k_wtrans<<<dim3(64,5,2),256,0,stream>>>(sw1l, sw2l, WT);
    k_modemix<<<288,512,0,stream>>>(XF, WT, XO);
    k_ispec<<<1608,256,0,stream>>>(XO, TB, TPK, Cb);
    k_gramC<<<dim3(9,BB),256,0,stream>>>(XO, GCp, SC);
    k_gramp<<<dim3(20,BB),256,0,stream>>>(A, Gpart, Spart, NN, NN);
    k_gramr<<<dim3(16,BB),256,0,stream>>>(Gpart, Spart, GFIN, SFIN, 80);
    k_statsA<<<32,256,0,stream>>>(GCp, SC, GFIN, SFIN,
          m1w + (size_t)l*4096, m1b + l*64, ww + (size_t)l*4096, wb + l*64,
          TSTAT, USTAT);
    k_fuse<<<dim3(316,BB),128,0,stream>>>(Cb, A,
          WPK + (size_t)(l*3+0)*4096, m1b + l*64, mg + l*64, mbt + l*64,
          WPK + (size_t)(l*3+1)*4096, m2b + l*64,
          WPK + (size_t)(l*3+2)*4096, wb  + l*64, ng + l*64, nb + l*64,
          TSTAT, USTAT, (l==3)?1:0);
  }

  k_gramp<<<dim3(18,BB),256,0,stream>>>(A, Gpart, Spart, SS, SS);
  k_gramr<<<dim3(16,BB),256,0,stream>>>(Gpart, Spart, GFIN, SFIN, 72);
  hipMemsetAsync(QP, 0, 32*sizeof(float), stream);
  k_statsQ<<<dim3(BB,4),256,0,stream>>>(GFIN, SFIN, q1w, q1b, QP);
  k_qfin<<<1,16,0,stream>>>(QP, QSTAT);
  k_qout<<<dim3(288,BB),256,0,stream>>>(A, WPK + (size_t)12*4096, q1b,
          qg, qbt, q2w, q2b, QSTAT, out);
}

// Round 22
// 817.655 us; speedup vs baseline: 2.6932x; 1.0035x over previous
//
#include <hip/hip_runtime.h>
#include <hip/hip_bf16.h>
#include <math.h>

// FNO2d: B=8, S=192, pad->201x201, C=64, modes 12x12, 4 layers.
// Pixel-major activations [b][p][c]; MFMA conv GEMMs; MFMA forward-W (dftw),
// MFMA H-DFT (dfthM); merged inverse+layer kernel k_ifuse (ispec->LDS->3 GEMMs,
// no Cb round-trip); chunked Parseval Gram; MFMA bypass Gram v2;
// fast sigmoid-gelu; bf16 spectral weights (WT); ILP-split qout.

#define NN 201
#define SS 192
#define NPIX 40401
#define QPIX 36864
#define BB 8
#define GNB 80           // gram slabs per b, 512 px each (one slab per wave)
#define XWPL 1234944     // 1608*12*64 (per-plane element stride; bf16)
#define PI_F 3.14159265358979323846f

typedef __hip_bfloat16 bf16;
typedef __attribute__((ext_vector_type(8))) short s8v;
typedef __attribute__((ext_vector_type(4))) float f32x4;

// tanh-form gelu via sigmoid: x*sigma(1.5957691x + 0.0713548x^3); |err| <= ~1e-3
__device__ __forceinline__ float gelu_f(float x){
  float x2 = x*x;
  float t  = fmaf(x2, 0.0713548162f, 1.5957691216f);
  float e  = __expf(-x*t);
  return x*__builtin_amdgcn_rcpf(1.0f+e);
}
__device__ __forceinline__ float b2f(bf16 v){ return __bfloat162float(v); }
__device__ __forceinline__ bf16  f2b(float v){ return __float2bfloat16(v); }
__device__ __forceinline__ unsigned short f2bu(float x){
  bf16 h = __float2bfloat16(x);
  unsigned short u; __builtin_memcpy(&u,&h,2); return u;
}
__device__ __forceinline__ float bu2f(unsigned short u){
  unsigned int x = ((unsigned int)u)<<16; float f; __builtin_memcpy(&f,&x,4); return f;
}

// tab[k][n]: cos/sin(2*pi*k*n/201), k=0..12, exact mod-201 reduction
__global__ void k_tab(float* __restrict__ tab){
  int t = blockIdx.x*blockDim.x+threadIdx.x;
  if(t>=13*NN) return;
  int k=t/NN, n=t-k*NN;
  int m=(k*n)%NN;
  float ang = (2.0f*PI_F/201.0f)*(float)m;
  tab[2*t]   = cosf(ang);
  tab[2*t+1] = sinf(ang);
}

// Pack inverse-W twiddles into MFMA A-fragment order (bf16).
__global__ void k_tpack(const float* __restrict__ tab, unsigned short* __restrict__ TPK){
  int e = blockIdx.x*256 + threadIdx.x;
  if(e>=6656) return;
  int wt=e>>9, lane=(e>>3)&63, j=e&7;
  int m_=lane&15, g=lane>>4;
  int w = wt*16+m_;
  int k24 = g*8+j;
  float v=0.f;
  if(k24<24 && w<201){
    float2 cs = ((const float2*)tab)[(k24>>1)*NN + w];
    v = (k24&1)? cs.y : cs.x;
  }
  TPK[e]=f2bu(v);
}

// Pack forward-W twiddles into MFMA A-fragment order (bf16), sign folded.
__global__ void k_tpack2(const float* __restrict__ tab, unsigned short* __restrict__ T2PK){
  int e = blockIdx.x*256 + threadIdx.x;
  if(e>=7168) return;
  int idx = e>>9;
  int mt = idx/7, chunk = idx - mt*7;
  int lane=(e>>3)&63, j=e&7;
  int m_=lane&15, g=lane>>4;
  int kx24 = mt*16 + m_;
  int w = chunk*32 + g*8 + j;
  float v=0.f;
  if(kx24<24 && w<NN){
    float2 cs = ((const float2*)tab)[(kx24>>1)*NN + w];
    v = (kx24&1)? -cs.y : cs.x;
  }
  T2PK[e]=f2bu(v);
}

// Pack H-DFT twiddles: M=48 rows (j24*2+comp), K=402 (re:k<201, im:k>=201).
__global__ void k_tpack3(const float* __restrict__ tab, unsigned short* __restrict__ T3PK){
  int e = blockIdx.x*256 + threadIdx.x;
  if(e>=19968) return;
  int idx=e>>9;
  int mt=idx/13, chunk=idx-mt*13;
  int lane=(e>>3)&63, j=e&7;
  int m_=lane&15, g=lane>>4;
  int m = mt*16+m_;
  int k = chunk*32+g*8+j;
  float v=0.f;
  if(m<48 && k<402){
    int j24=m>>1, comp=m&1;
    int k2=(j24<12)? j24 : 24-j24;
    float sgn=(j24<12)? -1.f : 1.f;
    int h=(k<201)? k : k-201;
    float2 cs=((const float2*)tab)[k2*NN+h];
    float cc=cs.x, ss=sgn*cs.y;
    if(k<201) v = comp? ss : cc;
    else      v = comp? cc : -ss;
  }
  T3PK[e]=f2bu(v);
}

// Separable encoder tables. grid (192,2), 64 thr.
__global__ void k_pretab(const float* __restrict__ Wp, const float* __restrict__ bp,
                         float* __restrict__ Ux, float* __restrict__ Uy){
  int i = blockIdx.x;
  int ax = blockIdx.y;
  int c = threadIdx.x;
  float g = (float)i*(1.0f/191.0f);
  float acc;
  if(ax==0) acc = bp[c] + g*Wp[64+c];
  else      acc = g*Wp[128+c];
  int cosBase = (ax==0)? 3 : 4;
  int sinBase = (ax==0)? 23 : 24;
  #pragma unroll
  for(int l=0;l<10;l++){
    float f = PI_F*(float)(1<<l);
    float sv,cv;
    sincosf(g*f,&sv,&cv);
    acc += cv*Wp[(cosBase+2*l)*64+c] + sv*Wp[(sinBase+2*l)*64+c];
  }
  float* U = (ax==0)? Ux : Uy;
  U[i*64+c] = acc;
}

// Pack 16 64x64 weight matrices into bf16 MFMA-fragment order.
__global__ void k_wpack(const float* __restrict__ m1w, const float* __restrict__ m2w,
                        const float* __restrict__ ww,  const float* __restrict__ q1w,
                        unsigned short* __restrict__ WPK){
  int bx = blockIdx.x, tid = threadIdx.x;
  const float* src;
  if(bx<12){
    int l=bx/3, sel=bx-l*3;
    src = (sel==0)? m1w+(size_t)l*4096 : (sel==1)? m2w+(size_t)l*4096 : ww+(size_t)l*4096;
  } else {
    src = q1w + (size_t)(bx-12)*4096;
  }
  unsigned short* dst = WPK + (size_t)bx*4096;
  #pragma unroll
  for(int t=0;t<16;t++){
    int d = tid*16+t;
    int frag=d>>9, lane=(d>>3)&63, j=d&7;
    int mt=frag>>1, kh=frag&1, m_=lane&15, g=lane>>4;
    dst[d] = f2bu(src[(size_t)(16*mt+m_)*64 + 32*kh + 8*g + j]);
  }
}

// Transpose spectral weights for layer into bf16 WT[m][comp][io].
__global__ void __launch_bounds__(256) k_wtrans(const float* __restrict__ w1,
        const float* __restrict__ w2, unsigned short* __restrict__ WT){
  __shared__ float tile[64][65];
  int io0 = blockIdx.x*64;
  int c0  = blockIdx.y*64;
  int z   = blockIdx.z;
  const float* src = (z==0)? w1 : w2;
  int tid = threadIdx.x;
  #pragma unroll
  for(int it=0;it<16;it++){
    int e = tid + 256*it;
    int r = e>>6, c = e&63;
    if(c0+c<288) tile[r][c] = src[(size_t)(io0+r)*288 + c0 + c];
  }
  __syncthreads();
  #pragma unroll
  for(int it=0;it<16;it++){
    int e = tid + 256*it;
    int rp = e>>6, cp = e&63;
    int col = c0 + rp;
    if(col<288){
      int ky = col/24, rm = col - ky*24;
      int kx = rm>>1, comp = rm&1;
      int m = z*144 + ky*12 + kx;
      WT[(size_t)m*8192 + comp*4096 + io0 + cp] = f2bu(tile[cp][rp]);
    }
  }
}

// encoder: A[b][p][c] = x*Wp0[c] + Ux[hh][c] + Uy[ww][c]; zeros in pad.
__global__ void k_encoder(const float* __restrict__ x, const float* __restrict__ Wp,
                          const float* __restrict__ Ux, const float* __restrict__ Uy,
                          bf16* __restrict__ A){
  int tid=threadIdx.x;
  int p = blockIdx.x*256+tid;
  if(p>=NPIX) return;
  int b = blockIdx.y;
  uint4* dst = (uint4*)(A + ((size_t)b*NPIX + p)*64);
  int hh=p/NN, ww=p-hh*NN;
  if(hh>=SS || ww>=SS){
    uint4 z = {0,0,0,0};
    #pragma unroll
    for(int i=0;i<8;i++) dst[i]=z;
    return;
  }
  float xv = x[((size_t)b*SS+hh)*SS+ww];
  const float4* ux = (const float4*)(Ux + hh*64);
  const float4* uy = (const float4*)(Uy + ww*64);
  const float4* w0 = (const float4*)Wp;
  #pragma unroll
  for(int i=0;i<8;i++){
    float4 a0 = ux[2*i],   a1 = ux[2*i+1];
    float4 b0 = uy[2*i],   b1 = uy[2*i+1];
    float4 c0 = w0[2*i],   c1 = w0[2*i+1];
    float v0=xv*c0.x+a0.x+b0.x, v1=xv*c0.y+a0.y+b0.y;
    float v2=xv*c0.z+a0.z+b0.z, v3=xv*c0.w+a0.w+b0.w;
    float v4=xv*c1.x+a1.x+b1.x, v5=xv*c1.y+a1.y+b1.y;
    float v6=xv*c1.z+a1.z+b1.z, v7=xv*c1.w+a1.w+b1.w;
    uint4 v;
    v.x = (unsigned)f2bu(v0) | ((unsigned)f2bu(v1)<<16);
    v.y = (unsigned)f2bu(v2) | ((unsigned)f2bu(v3)<<16);
    v.z = (unsigned)f2bu(v4) | ((unsigned)f2bu(v5)<<16);
    v.w = (unsigned)f2bu(v6) | ((unsigned)f2bu(v7)<<16);
    dst[i]=v;
  }
}

// MFMA forward DFT along W. grid 402 x 4 waves; wave = one row R=b*201+h.
__global__ void __launch_bounds__(256) k_dftw(const bf16* __restrict__ A,
        const unsigned short* __restrict__ T2PK, bf16* __restrict__ XWb){
  int tid=threadIdx.x, wid=tid>>6, l=tid&63;
  int m_=l&15, g=l>>4;
  int R = blockIdx.x*4 + wid;
  const bf16* row = A + (size_t)R*NN*64;
  f32x4 acc[2][4];
  #pragma unroll
  for(int mt=0;mt<2;mt++){
    #pragma unroll
    for(int nt=0;nt<4;nt++) acc[mt][nt]=f32x4{0.f,0.f,0.f,0.f};
  }
  for(int chunk=0;chunk<7;chunk++){
    int wbase = chunk*32 + g*8;
    s8v bf[4];
    if(chunk<6){
      #pragma unroll
      for(int nt=0;nt<4;nt++){
        s8v f;
        #pragma unroll
        for(int j=0;j<8;j++){
          unsigned short v;
          bf16 hv = row[(size_t)(wbase+j)*64 + 16*nt + m_];
          __builtin_memcpy(&v,&hv,2);
          f[j]=(short)v;
        }
        bf[nt]=f;
      }
    } else {
      #pragma unroll
      for(int nt=0;nt<4;nt++){
        s8v f;
        #pragma unroll
        for(int j=0;j<8;j++){
          unsigned short v=0;
          if(wbase+j<NN){
            bf16 hv = row[(size_t)(wbase+j)*64 + 16*nt + m_];
            __builtin_memcpy(&v,&hv,2);
          }
          f[j]=(short)v;
        }
        bf[nt]=f;
      }
    }
    #pragma unroll
    for(int mt=0;mt<2;mt++){
      s8v af = *(const s8v*)(T2PK + (size_t)(mt*7+chunk)*512 + l*8);
      #pragma unroll
      for(int nt=0;nt<4;nt++)
        acc[mt][nt]=__builtin_amdgcn_mfma_f32_16x16x32_bf16(af,bf[nt],acc[mt][nt],0,0,0);
    }
  }
  int bb = R/NN, h = R - bb*NN;
  #pragma unroll
  for(int mt=0;mt<2;mt++){
    #pragma unroll
    for(int nt=0;nt<4;nt++){
      #pragma unroll
      for(int e=0;e<4;e++){
        int kx24 = mt*16 + 4*g + e;
        if(kx24<24){
          int plane = kx24&1, kx = kx24>>1;
          XWb[(size_t)plane*XWPL + (((size_t)bb*12+kx)*201 + h)*64 + 16*nt + m_]
            = f2b(acc[mt][nt][e]);
        }
      }
    }
  }
}

// MFMA H-DFT: grid (12, BB, 2); 4 waves, wave wid<3 owns m-tile wid; z = nt-half.
__global__ void __launch_bounds__(256) k_dfthM(const bf16* __restrict__ XWb,
        const unsigned short* __restrict__ T3PK, float* __restrict__ XF){
  int kx=blockIdx.x, b=blockIdx.y, zh=blockIdx.z;
  int tid=threadIdx.x, wid=tid>>6, l=tid&63;
  int m_=l&15, g=l>>4;
  if(wid>=3) return;
  const bf16* base = XWb + (((size_t)b*12+kx)*201)*64;
  f32x4 acc0=f32x4{0.f,0.f,0.f,0.f}, acc1=f32x4{0.f,0.f,0.f,0.f};
  for(int chunk=0;chunk<13;chunk++){
    s8v bf0, bf1;
    #pragma unroll
    for(int nt2=0;nt2<2;nt2++){
      int c = 16*(zh*2+nt2) + m_;
      s8v f;
      #pragma unroll
      for(int j=0;j<8;j++){
        int k = chunk*32 + g*8 + j;
        unsigned short v=0;
        if(k<402){
          int h = (k<201)? k : (k-201);
          size_t poff = (k<201)? 0 : (size_t)XWPL;
          bf16 hv = base[poff + (size_t)h*64 + c];
          __builtin_memcpy(&v,&hv,2);
        }
        f[j]=(short)v;
      }
      if(nt2==0) bf0=f; else bf1=f;
    }
    s8v af = *(const s8v*)(T3PK + (size_t)(wid*13+chunk)*512 + l*8);
    acc0=__builtin_amdgcn_mfma_f32_16x16x32_bf16(af,bf0,acc0,0,0,0);
    acc1=__builtin_amdgcn_mfma_f32_16x16x32_bf16(af,bf1,acc1,0,0,0);
  }
  #pragma unroll
  for(int nt2=0;nt2<2;nt2++){
    f32x4 a = (nt2==0)? acc0 : acc1;
    int c = 16*(zh*2+nt2) + m_;
    #pragma unroll
    for(int e2=0;e2<4;e2++){
      int m = wid*16 + 4*g + e2;
      int j24 = m>>1, comp = m&1;
      XF[(size_t)(j24*12+kx)*1024 + ((size_t)b*64+c)*2 + comp] = a[e2];
    }
  }
}

// per-mode 64x64 complex mix; bf16 weights staged to fp32 LDS; ILP split accs.
__global__ void __launch_bounds__(512) k_modemix(const float* __restrict__ XF,
     const unsigned short* __restrict__ WT, float* __restrict__ XO){
  __shared__ float sx[1024];
  __shared__ float swr[4096], swi[4096];
  int m=blockIdx.x;
  int tid=threadIdx.x;
  sx[tid]     = XF[(size_t)m*1024+tid];
  sx[tid+512] = XF[(size_t)m*1024+tid+512];
  const unsigned short* wr = WT + (size_t)m*8192;
  const unsigned short* wi = wr + 4096;
  for(int io=tid;io<4096;io+=512){
    swr[io]=bu2f(wr[io]);
    swi[io]=bu2f(wi[io]);
  }
  __syncthreads();
  int b=tid>>6, o=tid&63;
  const float* xb = sx + b*128;
  float re0=0.f,re1=0.f,im0=0.f,im1=0.f;
  #pragma unroll 8
  for(int i=0;i<64;i+=2){
    float a=xb[2*i], b2=xb[2*i+1];
    float c=swr[i*64+o], d=swi[i*64+o];
    re0 = fmaf(a,c, fmaf(-b2,d, re0));
    im0 = fmaf(a,d, fmaf( b2,c, im0));
    float a1=xb[2*i+2], b3=xb[2*i+3];
    float c1=swr[(i+1)*64+o], d1=swi[(i+1)*64+o];
    re1 = fmaf(a1,c1, fmaf(-b3,d1, re1));
    im1 = fmaf(a1,d1, fmaf( b3,c1, im1));
  }
  XO[2*((size_t)m*512+tid)]  =re0+re1;
  XO[2*((size_t)m*512+tid)+1]=im0+im1;
}

// Merged inverse + fused layer. grid 1608 (rows R=b*201+h), 4 waves.
// Phase 1: idfth -> yl; phase 2: MFMA C2R -> cb[208][72] LDS (bf16 Cb row);
// phase 3: the 3 conv GEMMs on this row's 201 pixels (tiles 4/3/3/3 per wave;
// epilogue1 overwrites own tile rows of cb in place -> barrier-free).
__global__ void __launch_bounds__(256) k_ifuse(const float* __restrict__ XO,
    const float* __restrict__ tab, const unsigned short* __restrict__ TPK,
    bf16* __restrict__ A,
    const unsigned short* __restrict__ wp1, const float* __restrict__ m1b,
    const float* __restrict__ mg,  const float* __restrict__ mbt,
    const unsigned short* __restrict__ wp2, const float* __restrict__ m2b,
    const unsigned short* __restrict__ wpw, const float* __restrict__ wbk,
    const float* __restrict__ ng,  const float* __restrict__ nb,
    const float* __restrict__ tstat, const float* __restrict__ ustat, int last){
  __shared__ unsigned short cb[208][72];
  __shared__ float2 yl[12][64];
  __shared__ float2 cs13[13];
  int R=blockIdx.x;
  int b=R/NN, h=R-b*NN;
  int tid=threadIdx.x;
  if(tid<13) cs13[tid]=((const float2*)tab)[tid*NN+h];
  // zero pad rows 201..207 (7*72=504 shorts = 252 uints at short-offset 14472)
  for(int i=tid;i<252;i+=256) ((unsigned*)cb)[7236+i]=0u;
  __syncthreads();
  const float sc = 1.0f/40401.0f;
  #pragma unroll
  for(int it=0;it<3;it++){
    int item = tid + 256*it;
    int kx = item>>6, o = item&63;
    float re0=0.f,im0=0.f,re1=0.f,im1=0.f;
    #pragma unroll
    for(int j=0;j<24;j+=2){
      {
        int k2=(j<12)?j:24-j;
        float sgn=(j<12)?1.0f:-1.0f;
        float2 xo = *(const float2*)(XO + 2*(((size_t)(j*12+kx)*512) + b*64 + o));
        float2 cs = cs13[k2];
        float cc=cs.x, s2=sgn*cs.y;
        re0 = fmaf(xo.x,cc, fmaf(-xo.y,s2, re0));
        im0 = fmaf(xo.x,s2, fmaf( xo.y,cc, im0));
      }
      {
        int j1=j+1;
        int k2=(j1<12)?j1:24-j1;
        float sgn=(j1<12)?1.0f:-1.0f;
        float2 xo = *(const float2*)(XO + 2*(((size_t)(j1*12+kx)*512) + b*64 + o));
        float2 cs = cs13[k2];
        float cc=cs.x, s2=sgn*cs.y;
        re1 = fmaf(xo.x,cc, fmaf(-xo.y,s2, re1));
        im1 = fmaf(xo.x,s2, fmaf( xo.y,cc, im1));
      }
    }
    float fr = (kx==0)? sc : 2.0f*sc;
    float fi = (kx==0)? sc : -2.0f*sc;
    yl[kx][o] = float2{ (re0+re1)*fr, (im0+im1)*fi };
  }
  __syncthreads();
  int wid=tid>>6, l=tid&63, m_=l&15, g=l>>4;
  {
    int o = wid*16 + m_;
    s8v bfr;
    #pragma unroll
    for(int j=0;j<4;j++){
      float2 v = yl[4*g+j][o];
      bfr[2*j]   = (short)f2bu(v.x);
      bfr[2*j+1] = (short)f2bu(v.y);
    }
    #pragma unroll
    for(int wt=0; wt<13; wt++){
      s8v af0 = *(const s8v*)(TPK + (size_t)wt*512 + l*8);
      f32x4 acc0 = f32x4{0.f,0.f,0.f,0.f};
      acc0 = __builtin_amdgcn_mfma_f32_16x16x32_bf16(af0, bfr, acc0, 0,0,0);
      #pragma unroll
      for(int e=0;e<4;e++){
        int w = wt*16 + 4*g + e;
        if(w<NN) cb[w][o] = f2bu(acc0[e]);
      }
    }
  }
  __syncthreads();
  // ---- fuse phase: tiles t_=wid+4*nt (13 total; wave0 gets 4) ----
  const bf16* ab = A + (size_t)b*NPIX*64;
  int ntv = (wid==0)? 4 : 3;
  s8v af[4][2];
  f32x4 acc[4][4];
  // GEMM1: t = m1w @ cb + m1b
  #pragma unroll
  for(int mt=0;mt<4;mt++){
    #pragma unroll
    for(int kh=0;kh<2;kh++)
      af[mt][kh]=*(const s8v*)(wp1 + (mt*2+kh)*512 + l*8);
    float4 b4 = *(const float4*)(m1b + 16*mt + 4*g);
    #pragma unroll
    for(int nt=0;nt<4;nt++) acc[mt][nt]=f32x4{b4.x,b4.y,b4.z,b4.w};
  }
  #pragma unroll
  for(int nt=0;nt<4;nt++){
    if(nt>=ntv) continue;
    int row = 16*(wid+4*nt) + m_;
    const s8v* vp = (const s8v*)&cb[row][0];
    s8v b0 = vp[g], b1 = vp[4+g];
    #pragma unroll
    for(int mt=0;mt<4;mt++){
      acc[mt][nt]=__builtin_amdgcn_mfma_f32_16x16x32_bf16(af[mt][0],b0,acc[mt][nt],0,0,0);
      acc[mt][nt]=__builtin_amdgcn_mfma_f32_16x16x32_bf16(af[mt][1],b1,acc[mt][nt],0,0,0);
    }
  }
  // epilogue1: GN+gelu -> cb tile rows (wave-exclusive, in place)
  {
    float tm0=tstat[b*4],tr0=tstat[b*4+1],tm1=tstat[b*4+2],tr1=tstat[b*4+3];
    #pragma unroll
    for(int mt=0;mt<4;mt++){
      float4 g4 = *(const float4*)(mg  + 16*mt + 4*g);
      float4 t4 = *(const float4*)(mbt + 16*mt + 4*g);
      float mn = (mt<2)? tm0 : tm1;
      float rs = (mt<2)? tr0 : tr1;
      float ax=rs*g4.x, ay=rs*g4.y, az=rs*g4.z, aw=rs*g4.w;
      float cx=t4.x-mn*ax, cy=t4.y-mn*ay, cz=t4.z-mn*az, cw=t4.w-mn*aw;
      #pragma unroll
      for(int nt=0;nt<4;nt++){
        if(nt>=ntv) continue;
        int row = 16*(wid+4*nt) + m_;
        f32x4 t = acc[mt][nt];
        float v0 = gelu_f(fmaf(t[0],ax,cx));
        float v1 = gelu_f(fmaf(t[1],ay,cy));
        float v2 = gelu_f(fmaf(t[2],az,cz));
        float v3 = gelu_f(fmaf(t[3],aw,cw));
        uint2 pk;
        pk.x = (unsigned)f2bu(v0) | ((unsigned)f2bu(v1)<<16);
        pk.y = (unsigned)f2bu(v2) | ((unsigned)f2bu(v3)<<16);
        *(uint2*)&cb[row][16*mt+4*g] = pk;
      }
    }
  }
  // GEMM3: u = ww @ A + wb (global bypass read; overlaps epilogue latency)
  #pragma unroll
  for(int mt=0;mt<4;mt++){
    #pragma unroll
    for(int kh=0;kh<2;kh++)
      af[mt][kh]=*(const s8v*)(wpw + (mt*2+kh)*512 + l*8);
    float4 b4 = *(const float4*)(wbk + 16*mt + 4*g);
    #pragma unroll
    for(int nt=0;nt<4;nt++) acc[mt][nt]=f32x4{b4.x,b4.y,b4.z,b4.w};
  }
  #pragma unroll
  for(int nt=0;nt<4;nt++){
    if(nt>=ntv) continue;
    int w = 16*(wid+4*nt) + m_;
    int wc = (w<NN)? w : (NN-1);
    const s8v* xb = (const s8v*)(ab + (size_t)(h*NN + wc)*64);
    s8v b0 = xb[g], b1 = xb[4+g];
    #pragma unroll
    for(int mt=0;mt<4;mt++){
      acc[mt][nt]=__builtin_amdgcn_mfma_f32_16x16x32_bf16(af[mt][0],b0,acc[mt][nt],0,0,0);
      acc[mt][nt]=__builtin_amdgcn_mfma_f32_16x16x32_bf16(af[mt][1],b1,acc[mt][nt],0,0,0);
    }
  }
  // epilogue3: acc = m2b + GN(u)
  {
    float um0=ustat[b*4],ur0=ustat[b*4+1],um1=ustat[b*4+2],ur1=ustat[b*4+3];
    #pragma unroll
    for(int mt=0;mt<4;mt++){
      float4 n4 = *(const float4*)(ng  + 16*mt + 4*g);
      float4 nb4= *(const float4*)(nb  + 16*mt + 4*g);
      float4 m24= *(const float4*)(m2b + 16*mt + 4*g);
      float mn = (mt<2)? um0 : um1;
      float rs = (mt<2)? ur0 : ur1;
      float ax=rs*n4.x, ay=rs*n4.y, az=rs*n4.z, aw=rs*n4.w;
      float cx=m24.x+nb4.x-mn*ax, cy=m24.y+nb4.y-mn*ay;
      float cz=m24.z+nb4.z-mn*az, cw=m24.w+nb4.w-mn*aw;
      #pragma unroll
      for(int nt=0;nt<4;nt++){
        f32x4 u = acc[mt][nt];
        u[0] = fmaf(u[0],ax,cx);
        u[1] = fmaf(u[1],ay,cy);
        u[2] = fmaf(u[2],az,cz);
        u[3] = fmaf(u[3],aw,cw);
        acc[mt][nt]=u;
      }
    }
  }
  // GEMM2: acc += m2w @ v (re-reads own tile rows of cb)
  #pragma unroll
  for(int mt=0;mt<4;mt++){
    #pragma unroll
    for(int kh=0;kh<2;kh++)
      af[mt][kh]=*(const s8v*)(wp2 + (mt*2+kh)*512 + l*8);
  }
  #pragma unroll
  for(int nt=0;nt<4;nt++){
    if(nt>=ntv) continue;
    int row = 16*(wid+4*nt) + m_;
    const s8v* vp = (const s8v*)&cb[row][0];
    s8v b0 = vp[g], b1 = vp[4+g];
    #pragma unroll
    for(int mt=0;mt<4;mt++){
      acc[mt][nt]=__builtin_amdgcn_mfma_f32_16x16x32_bf16(af[mt][0],b0,acc[mt][nt],0,0,0);
      acc[mt][nt]=__builtin_amdgcn_mfma_f32_16x16x32_bf16(af[mt][1],b1,acc[mt][nt],0,0,0);
    }
  }
  // final: h = gelu?(x1+x2) -> A
  #pragma unroll
  for(int nt=0;nt<4;nt++){
    if(nt>=ntv) continue;
    int w = 16*(wid+4*nt) + m_;
    if(w>=NN) continue;
    bf16* dp = A + ((size_t)b*NPIX + (size_t)h*NN + w)*64;
    #pragma unroll
    for(int mt=0;mt<4;mt++){
      f32x4 hh = acc[mt][nt];
      float h0=hh[0],h1=hh[1],h2=hh[2],h3=hh[3];
      if(!last){ h0=gelu_f(h0); h1=gelu_f(h1); h2=gelu_f(h2); h3=gelu_f(h3); }
      uint2 pk;
      pk.x = (unsigned)f2bu(h0) | ((unsigned)f2bu(h1)<<16);
      pk.y = (unsigned)f2bu(h2) | ((unsigned)f2bu(h3)<<16);
      *(uint2*)(dp + 16*mt + 4*g) = pk;
    }
  }
}

// Chunked Parseval Gram from XO: grid (9, BB). Block = 64-feature chunk.
__global__ void __launch_bounds__(256) k_gramC(const float* __restrict__ XO,
        float* __restrict__ GCp, float* __restrict__ SC){
  __shared__ unsigned short V[64][72];
  int chunk=blockIdx.x, b=blockIdx.y, tid=threadIdx.x;
  const float s1=1.0f/201.0f;
  const float r2=0.70710678118f;
  const float q2=1.41421356237f;
  #pragma unroll
  for(int it=0;it<16;it++){
    int e = tid + it*256;
    int fl=e>>6, ch=e&63;
    int f = chunk*64 + fl;
    int base = b*64+ch;
    float v=0.f;
    if(f<528){
      int comp=f&1, kxm=f>>1;
      int kx0=kxm/24;
      int kx=1+kx0, m=kxm-kx0*24;
      v = q2*XO[2*((size_t)(m*12+kx)*512 + base)+comp];
    } else if(f==528){
      v = XO[2*(size_t)base];
    } else if(f<551){
      int q=f-529; int mm=1+(q>>1);
      const float* p1 = XO + 2*((size_t)(mm*12)*512 + base);
      const float* p2 = XO + 2*((size_t)((24-mm)*12)*512 + base);
      v = ((q&1)==0)? r2*(p1[0]+p2[0]) : r2*(p1[1]-p2[1]);
    } else if(f==551){
      v = r2*XO[2*((size_t)(144)*512 + base)];
    } else if(f==552){
      v = r2*XO[2*((size_t)(144)*512 + base)+1];
    }
    V[ch][fl]=f2bu(v*s1);
  }
  __syncthreads();
  int wid=tid>>6, l=tid&63, m_=l&15, g=l>>4;
  f32x4 acc[4];
  #pragma unroll
  for(int mt=0;mt<4;mt++) acc[mt]=f32x4{0.f,0.f,0.f,0.f};
  #pragma unroll
  for(int kc=0;kc<2;kc++){
    s8v bfr = *(const s8v*)&V[16*wid+m_][kc*32+8*g];
    #pragma unroll
    for(int mt=0;mt<4;mt++){
      s8v afr = *(const s8v*)&V[16*mt+m_][kc*32+8*g];
      acc[mt]=__builtin_amdgcn_mfma_f32_16x16x32_bf16(afr,bfr,acc[mt],0,0,0);
    }
  }
  float* gb = GCp + ((size_t)(b*9+chunk))*4096;
  #pragma unroll
  for(int mt=0;mt<4;mt++){
    #pragma unroll
    for(int e=0;e<4;e++)
      gb[(size_t)(16*mt+4*g+e)*64 + 16*wid + m_] = acc[mt][e];
  }
  if(chunk==0 && tid<64) SC[b*64+tid] = XO[2*(size_t)(b*64+tid)];
}

// MFMA Gram v2: fragments loaded directly from global. grid (nblkx, BB) x 4 waves.
__global__ void __launch_bounds__(256) k_gramp(const bf16* __restrict__ X,
        float* __restrict__ Gpart, float* __restrict__ Spart, int HR, int WR){
  int b = blockIdx.y, blk = blockIdx.x;
  int npix = HR*WR;
  int tid=threadIdx.x, wid=tid>>6, l=tid&63;
  int m_=l&15, g=l>>4;
  int slab = blk*4 + wid;
  const bf16* xb = X + (size_t)b*NPIX*64;
  f32x4 acc[4][4];
  #pragma unroll
  for(int mt=0;mt<4;mt++){
    #pragma unroll
    for(int nt=0;nt<4;nt++) acc[mt][nt]=f32x4{0.f,0.f,0.f,0.f};
  }
  float cs[4]={0.f,0.f,0.f,0.f};
  for(int kc=0;kc<16;kc++){
    int pbase = slab*512 + kc*32 + g*8;
    int hh0=0, ww0=0;
    if(WR!=NN){ hh0 = pbase/WR; ww0 = pbase - hh0*WR; }
    const bf16* ptr[8];
    #pragma unroll
    for(int jj=0;jj<8;jj++){
      int p = pbase + jj;
      int gp;
      if(WR==NN) gp = p;
      else {
        int ww2 = ww0 + jj;
        int hh  = hh0;
        if(ww2>=WR){ ww2-=WR; hh++; }
        gp = hh*NN + ww2;
      }
      ptr[jj] = (p<npix) ? (xb + (size_t)gp*64) : (const bf16*)0;
    }
    s8v fr[4];
    #pragma unroll
    for(int t=0;t<4;t++){
      s8v f;
      float s=0.f;
      #pragma unroll
      for(int jj=0;jj<8;jj++){
        unsigned short v=0;
        if(ptr[jj]){ bf16 hv = ptr[jj][16*t+m_]; __builtin_memcpy(&v,&hv,2); }
        f[jj]=(short)v;
        s += bu2f(v);
      }
      fr[t]=f;
      cs[t]+=s;
    }
    #pragma unroll
    for(int nt=0;nt<4;nt++){
      #pragma unroll
      for(int mt=0;mt<4;mt++)
        acc[mt][nt]=__builtin_amdgcn_mfma_f32_16x16x32_bf16(fr[mt],fr[nt],acc[mt][nt],0,0,0);
    }
  }
  float* gp_ = Gpart + ((size_t)(b*GNB + slab))*4096;
  #pragma unroll
  for(int mt=0;mt<4;mt++){
    #pragma unroll
    for(int nt=0;nt<4;nt++){
      #pragma unroll
      for(int e=0;e<4;e++)
        gp_[(size_t)(16*mt + 4*g + e)*64 + 16*nt + m_] = acc[mt][nt][e];
    }
  }
  #pragma unroll
  for(int t=0;t<4;t++){
    float s=cs[t];
    s += __shfl_xor(s,16,64);
    s += __shfl_xor(s,32,64);
    if(g==0) Spart[((size_t)(b*GNB+slab))*64 + 16*t + m_] = s;
  }
}

// Parallel slab reduce: grid (16, BB). Gfin[b][4096], Sfin[b][64].
__global__ void __launch_bounds__(256) k_gramr(const float* __restrict__ Gpart,
        const float* __restrict__ Spart, float* __restrict__ Gfin,
        float* __restrict__ Sfin, int nblk){
  int b = blockIdx.y;
  int idx = blockIdx.x*256 + threadIdx.x;
  float s0=0.f,s1=0.f,s2=0.f,s3=0.f;
  int k=0;
  for(;k+3<nblk;k+=4){
    s0 += Gpart[((size_t)b*GNB + k  )*4096 + idx];
    s1 += Gpart[((size_t)b*GNB + k+1)*4096 + idx];
    s2 += Gpart[((size_t)b*GNB + k+2)*4096 + idx];
    s3 += Gpart[((size_t)b*GNB + k+3)*4096 + idx];
  }
  for(;k<nblk;k++) s0 += Gpart[((size_t)b*GNB + k)*4096 + idx];
  Gfin[(size_t)b*4096 + idx] = (s0+s1)+(s2+s3);
  if(blockIdx.x==0 && threadIdx.x<64){
    float ss=0.f;
    for(int j=0;j<nblk;j++) ss += Spart[((size_t)b*GNB + j)*64 + threadIdx.x];
    Sfin[b*64 + threadIdx.x]=ss;
  }
}

// Stats for layer (grid 32): zb2 = zb*2+grp. zb<8 -> Cb (chunked GCp + SC);
// zb>=8 -> A (Gfin/Sfin). Block = one GN group of 32 rows; i split 8-ways.
__global__ void __launch_bounds__(256) k_statsA(
        const float* __restrict__ GCp, const float* __restrict__ SC,
        const float* __restrict__ Gfin, const float* __restrict__ Sfin,
        const float* __restrict__ m1wl, const float* __restrict__ m1bl,
        const float* __restrict__ wwl,  const float* __restrict__ wbl,
        float* __restrict__ TSTAT, float* __restrict__ USTAT){
  __shared__ float Gs[4096];
  __shared__ float Ss[64];
  __shared__ float rs[256], rq[256];
  int zb2=blockIdx.x;
  int zb=zb2>>1, grp=zb2&1;
  int t=threadIdx.x;
  if(zb<8){
    #pragma unroll
    for(int e=0;e<16;e++){
      float s=0.f;
      #pragma unroll
      for(int q=0;q<9;q++) s += GCp[((size_t)(zb*9+q))*4096 + t*16+e];
      Gs[t*16+e]=s;
    }
    if(t<64) Ss[t]=SC[zb*64+t];
  } else {
    const float* GS = Gfin + (size_t)(zb-8)*4096;
    #pragma unroll
    for(int e=0;e<16;e++) Gs[t*16+e]=GS[t*16+e];
    if(t<64) Ss[t]=Sfin[(zb-8)*64+t];
  }
  __syncthreads();
  const float* W    = (zb<8)? m1wl : wwl;
  const float* bias = (zb<8)? m1bl : wbl;
  float* stat       = (zb<8)? TSTAT : USTAT;
  int b = (zb<8)? zb : zb-8;
  int o = grp*32 + (t&31);
  int sl = t>>5;
  float w[64];
  #pragma unroll
  for(int j2=0;j2<64;j2++) w[j2]=bu2f(f2bu(W[(size_t)o*64+j2]));
  const float* Gr = Gs + (size_t)(sl*8)*64;
  float quad=0.f;
  #pragma unroll
  for(int r=0;r<8;r++){
    const float* gr = Gr + r*64;
    float tt=0.f;
    #pragma unroll
    for(int j2=0;j2<64;j2++) tt += gr[j2]*w[j2];
    quad += w[sl*8+r]*tt;
  }
  float sm=0.f, sq=quad;
  if(sl==0){
    float dot=0.f;
    #pragma unroll
    for(int j2=0;j2<64;j2++) dot += w[j2]*Ss[j2];
    float bo = bias[o];
    float Nf = (float)NPIX;
    sm = dot + Nf*bo;
    sq += 2.f*bo*dot + Nf*bo*bo;
  }
  rs[t]=sm; rq[t]=sq;
  __syncthreads();
  if(t<32){
    float s2=0.f,q2=0.f;
    #pragma unroll
    for(int k=0;k<8;k++){ s2+=rs[t+32*k]; q2+=rq[t+32*k]; }
    for(int off=16;off>0;off>>=1){
      s2 += __shfl_down(s2,off,32);
      q2 += __shfl_down(q2,off,32);
    }
    if(t==0){
      float invN = 1.f/((float)NPIX*32.f);
      float mean = s2*invN;
      float var = q2*invN - mean*mean;
      stat[b*4+grp*2]   = mean;
      stat[b*4+grp*2+1] = rsqrtf(fmaxf(var,0.f)+1e-5f);
    }
  }
}

// Head stats partials: grid (BB, 4). Block = 64 rows; i split 4-ways.
__global__ void __launch_bounds__(256) k_statsQ(const float* __restrict__ Gfin,
        const float* __restrict__ Sfin,
        const float* __restrict__ W, const float* __restrict__ bias,
        float* __restrict__ QP){
  __shared__ float Gs[4096];
  __shared__ float Ss[64];
  __shared__ float rs[256], rq[256];
  int b=blockIdx.x, z=blockIdx.y, t=threadIdx.x;
  #pragma unroll
  for(int e=0;e<16;e++) Gs[t*16+e]=Gfin[(size_t)b*4096 + t*16+e];
  if(t<64) Ss[t]=Sfin[b*64+t];
  __syncthreads();
  int o = z*64 + (t&63);
  int sl = t>>6;
  float w[64];
  #pragma unroll
  for(int j2=0;j2<64;j2++) w[j2]=bu2f(f2bu(W[(size_t)o*64+j2]));
  const float* Gr = Gs + (size_t)(sl*16)*64;
  float quad=0.f;
  #pragma unroll
  for(int r=0;r<16;r++){
    const float* gr = Gr + r*64;
    float tt=0.f;
    #pragma unroll
    for(int j2=0;j2<64;j2++) tt += gr[j2]*w[j2];
    quad += w[sl*16+r]*tt;
  }
  float sm=0.f, sq=quad;
  if(sl==0){
    float dot=0.f;
    #pragma unroll
    for(int j2=0;j2<64;j2++) dot += w[j2]*Ss[j2];
    float bo=bias[o];
    float Nf=(float)QPIX;
    sm = dot + Nf*bo;
    sq += 2.f*bo*dot + Nf*bo*bo;
  }
  rs[t]=sm; rq[t]=sq;
  __syncthreads();
  if(t<64){
    float s2 = rs[t]+rs[t+64]+rs[t+128]+rs[t+192];
    float q2 = rq[t]+rq[t+64]+rq[t+128]+rq[t+192];
    for(int off=32;off>0;off>>=1){
      s2 += __shfl_down(s2,off,64);
      q2 += __shfl_down(q2,off,64);
    }
    if(t==0){
      int g = z>>1;
      atomicAdd(&QP[b*4+g*2],   s2);
      atomicAdd(&QP[b*4+g*2+1], q2);
    }
  }
}

// Finalize head stats. grid 1, 16 threads.
__global__ void k_qfin(const float* __restrict__ QP, float* __restrict__ QSTAT){
  int t=threadIdx.x;
  if(t>=16) return;
  int b=t>>1, g=t&1;
  float s=QP[b*4+g*2], ss=QP[b*4+g*2+1];
  float invN=1.f/((float)QPIX*128.f);
  float mean=s*invN, var=ss*invN-mean*mean;
  QSTAT[b*4+g*2]   = mean;
  QSTAT[b*4+g*2+1] = rsqrtf(fmaxf(var,0.f)+1e-5f);
}

// Head: 128px/block (grid 288,BB); wave = one oc chunk over 8 nt; folded GN
// coeffs; 4 independent gelu-dot accumulators (ILP).
__global__ void __launch_bounds__(256) k_qout(const bf16* __restrict__ A,
    const unsigned short* __restrict__ qpack, const float* __restrict__ q1b,
    const float* __restrict__ qg, const float* __restrict__ qbt,
    const float* __restrict__ q2w, const float* __restrict__ q2b,
    const float* __restrict__ qstat, float* __restrict__ out){
  __shared__ unsigned short xq[128][72];
  __shared__ float part[4][128];
  int tid=threadIdx.x;
  int wid=tid>>6, l=tid&63;
  int m_=l&15, g=l>>4;
  int b=blockIdx.y;
  int px0=blockIdx.x*128;
  {
    int p = px0 + (tid>>1);
    int half = tid&1;
    int hh=p/SS, ww2=p-hh*SS;
    const uint4* src=(const uint4*)(A + (((size_t)b*NPIX) + (size_t)hh*NN + ww2)*64 + half*32);
    uint4* drow=(uint4*)&xq[tid>>1][half*32];
    #pragma unroll
    for(int i=0;i<4;i++) drow[i]=src[i];
  }
  __syncthreads();
  int oc=wid;
  const unsigned short* wp = qpack + (size_t)oc*4096;
  s8v af[4][2];
  f32x4 bi4[4];
  float4 a4[4], c4[4], w4[4];
  float m0=qstat[b*4],r0=qstat[b*4+1],m1=qstat[b*4+2],r1=qstat[b*4+3];
  float mn=(oc<2)?m0:m1, rs=(oc<2)?r0:r1;
  #pragma unroll
  for(int mt=0;mt<4;mt++){
    #pragma unroll
    for(int kh=0;kh<2;kh++)
      af[mt][kh]=*(const s8v*)(wp + (mt*2+kh)*512 + l*8);
    float4 b4=*(const float4*)(q1b + 64*oc + 16*mt + 4*g);
    bi4[mt]=f32x4{b4.x,b4.y,b4.z,b4.w};
    float4 g4=*(const float4*)(qg  + 64*oc + 16*mt + 4*g);
    float4 t4=*(const float4*)(qbt + 64*oc + 16*mt + 4*g);
    w4[mt]=*(const float4*)(q2w + 64*oc + 16*mt + 4*g);
    a4[mt]=float4{rs*g4.x, rs*g4.y, rs*g4.z, rs*g4.w};
    c4[mt]=float4{t4.x-mn*a4[mt].x, t4.y-mn*a4[mt].y, t4.z-mn*a4[mt].z, t4.w-mn*a4[mt].w};
  }
  #pragma unroll
  for(int nt=0;nt<8;nt++){
    const s8v* vp = (const s8v*)&xq[16*nt+m_][0];
    s8v b0=vp[g], b1=vp[4+g];
    f32x4 acc[4];
    #pragma unroll
    for(int mt=0;mt<4;mt++) acc[mt]=bi4[mt];
    #pragma unroll
    for(int mt=0;mt<4;mt++){
      acc[mt]=__builtin_amdgcn_mfma_f32_16x16x32_bf16(af[mt][0],b0,acc[mt],0,0,0);
      acc[mt]=__builtin_amdgcn_mfma_f32_16x16x32_bf16(af[mt][1],b1,acc[mt],0,0,0);
    }
    float ppv[4];
    #pragma unroll
    for(int mt=0;mt<4;mt++){
      f32x4 t=acc[mt];
      float q0 = gelu_f(fmaf(t[0],a4[mt].x,c4[mt].x))*w4[mt].x;
      float q1 = gelu_f(fmaf(t[1],a4[mt].y,c4[mt].y))*w4[mt].y;
      float q2 = gelu_f(fmaf(t[2],a4[mt].z,c4[mt].z))*w4[mt].z;
      float q3 = gelu_f(fmaf(t[3],a4[mt].w,c4[mt].w))*w4[mt].w;
      ppv[mt] = (q0+q1)+(q2+q3);
    }
    float pp = (ppv[0]+ppv[1])+(ppv[2]+ppv[3]);
    pp += __shfl_xor(pp,16,64);
    pp += __shfl_xor(pp,32,64);
    if(g==0) part[wid][16*nt+m_]=pp;
  }
  __syncthreads();
  if(tid<128)
    out[(size_t)b*QPIX + px0 + tid] =
        q2b[0] + part[0][tid]+part[1][tid]+part[2][tid]+part[3][tid];
}

extern "C" void kernel_launch(void* const* d_in, const int* in_sizes, int n_in,
                              void* d_out, int out_size, void* d_ws, size_t ws_size,
                              hipStream_t stream){
  const float* x   = (const float*)d_in[0];
  const float* Wp  = (const float*)d_in[1];
  const float* bp  = (const float*)d_in[2];
  const float* sw1 = (const float*)d_in[3];
  const float* sw2 = (const float*)d_in[4];
  const float* m1w = (const float*)d_in[5];
  const float* m1b = (const float*)d_in[6];
  const float* mg  = (const float*)d_in[7];
  const float* mbt = (const float*)d_in[8];
  const float* m2w = (const float*)d_in[9];
  const float* m2b = (const float*)d_in[10];
  const float* ww  = (const float*)d_in[11];
  const float* wb  = (const float*)d_in[12];
  const float* ng  = (const float*)d_in[13];
  const float* nb  = (const float*)d_in[14];
  const float* q1w = (const float*)d_in[15];
  const float* q1b = (const float*)d_in[16];
  const float* qg  = (const float*)d_in[17];
  const float* qbt = (const float*)d_in[18];
  const float* q2w = (const float*)d_in[19];
  const float* q2b = (const float*)d_in[20];
  float* out = (float*)d_out;

  char* w8 = (char*)d_ws;
  const size_t ACT_B = (size_t)64*BB*NPIX*sizeof(bf16);   // 41,370,624
  bf16*  A    = (bf16*)(w8);
  bf16*  Cb   = (bf16*)(w8 + ACT_B);                       // (unused; kept for layout)
  float* SPEC = (float*)(w8 + 2*ACT_B);                    // XWb / Gpart overlays
  float* XF   = (float*)(w8 + 2*ACT_B + 9879552);
  float* XO   = (float*)(w8 + 2*ACT_B + 9879552 + 1179648);
  float* TB   = (float*)(w8 + 2*ACT_B + 9879552 + 2*1179648);
  char*  g8   = w8 + 2*ACT_B + 9879552 + 2*1179648 + 20992;
  float* TSTAT= (float*)g8;
  float* USTAT= TSTAT + 32;
  float* QSTAT= USTAT + 32;
  float* UxT  = QSTAT + 32;                  // 192*64
  float* UyT  = UxT + 12288;                 // 192*64
  unsigned short* WPK = (unsigned short*)(UyT + 12288);   // 16*4096 bf16
  float* GFIN = (float*)(WPK + 16*4096);     // 8*4096 (reduced bypass gram)
  float* SFIN = GFIN + 8*4096;               // 8*64
  float* SC   = SFIN + 8*64;                 // 8*64 (Parseval col sums)
  unsigned short* TPK = (unsigned short*)(SC + 8*64);     // 13*512 inverse twiddles
  unsigned short* T2PK = TPK + 6656;                      // 14*512 forward twiddles
  unsigned short* T3PK = T2PK + 7168;                     // 39*512 H-DFT twiddles
  float* QP   = (float*)(T3PK + 19968);      // 32 (head stat partials)
  float* GCp  = QP + 32;                     // 8*9*4096 (Parseval partials)
  unsigned short* WT = (unsigned short*)(GCp + (size_t)8*9*4096); // 288*8192 bf16
  bf16*  XWb  = (bf16*)SPEC;                 // 2*XWPL bf16 = 4.94MB (SPEC overlay)
  float* Gpart = SPEC;                       // 8*80*4096 fl = 10.49MB <= SPEC+XF
  float* Spart = Gpart + (size_t)8*GNB*4096;
  size_t needed = (size_t)(2*ACT_B) + 9879552 + 2*1179648 + 20992
                + 3*32*4 + 2*12288*4 + 16*4096*2 + (8*4096+2*8*64)*4
                + 13312 + 14336 + 39936 + 128
                + (size_t)8*9*4096*4 + (size_t)288*8192*2;
  if(ws_size < needed) return;
  (void)Cb;

  k_tab<<<11,256,0,stream>>>(TB);
  k_tpack<<<26,256,0,stream>>>(TB, TPK);
  k_tpack2<<<28,256,0,stream>>>(TB, T2PK);
  k_tpack3<<<78,256,0,stream>>>(TB, T3PK);
  k_pretab<<<dim3(192,2),64,0,stream>>>(Wp, bp, UxT, UyT);
  k_wpack<<<16,256,0,stream>>>(m1w, m2w, ww, q1w, WPK);
  k_encoder<<<dim3(158,BB),256,0,stream>>>(x, Wp, UxT, UyT, A);

  for(int l=0;l<4;l++){
    const float* sw1l = sw1 + (size_t)l*1179648;
    const float* sw2l = sw2 + (size_t)l*1179648;
    k_dftw<<<402,256,0,stream>>>(A, T2PK, XWb);
    k_dfthM<<<dim3(12,BB,2),256,0,stream>>>(XWb, T3PK, XF);
    k_wtrans<<<dim3(64,5,2),256,0,stream>>>(sw1l, sw2l, WT);
    k_modemix<<<288,512,0,stream>>>(XF, WT, XO);
    k_gramC<<<dim3(9,BB),256,0,stream>>>(XO, GCp, SC);
    k_gramp<<<dim3(20,BB),256,0,stream>>>(A, Gpart, Spart, NN, NN);
    k_gramr<<<dim3(16,BB),256,0,stream>>>(Gpart, Spart, GFIN, SFIN, 80);
    k_statsA<<<32,256,0,stream>>>(GCp, SC, GFIN, SFIN,
          m1w + (size_t)l*4096, m1b + l*64, ww + (size_t)l*4096, wb + l*64,
          TSTAT, USTAT);
    k_ifuse<<<1608,256,0,stream>>>(XO, TB, TPK, A,
          WPK + (size_t)(l*3+0)*4096, m1b + l*64, mg + l*64, mbt + l*64,
          WPK + (size_t)(l*3+1)*4096, m2b + l*64,
          WPK + (size_t)(l*3+2)*4096, wb  + l*64, ng + l*64, nb + l*64,
          TSTAT, USTAT, (l==3)?1:0);
  }

  k_gramp<<<dim3(18,BB),256,0,stream>>>(A, Gpart, Spart, SS, SS);
  k_gramr<<<dim3(16,BB),256,0,stream>>>(Gpart, Spart, GFIN, SFIN, 72);
  hipMemsetAsync(QP, 0, 32*sizeof(float), stream);
  k_statsQ<<<dim3(BB,4),256,0,stream>>>(GFIN, SFIN, q1w, q1b, QP);
  k_qfin<<<1,16,0,stream>>>(QP, QSTAT);
  k_qout<<<dim3(288,BB),256,0,stream>>>(A, WPK + (size_t)12*4096, q1b,
          qg, qbt, q2w, q2b, QSTAT, out);
}